// Round 2
// baseline (258.340 us; speedup 1.0000x reference)
//
#include <hip/hip_runtime.h>
#include <hip/hip_bf16.h>

// Problem constants
#define NB  2      // batch
#define CC  256    // channels
#define NHD 8      // heads
#define HD  32     // head dim
#define NT  4096   // tokens = H*W

typedef __bf16 bf16x8 __attribute__((ext_vector_type(8)));
typedef bf16x8 bf16x8_ma __attribute__((may_alias));
typedef __bf16 bf16x4 __attribute__((ext_vector_type(4)));
typedef bf16x4 bf16x4_ma __attribute__((may_alias));
typedef float  f32x4  __attribute__((ext_vector_type(4)));
typedef float  f32x16 __attribute__((ext_vector_type(16)));
typedef unsigned int u32x4 __attribute__((ext_vector_type(4)));

static __device__ __forceinline__ f32x4 zero4() {
    f32x4 z = {0.f, 0.f, 0.f, 0.f}; return z;
}
static __device__ __forceinline__ f32x16 zero16() {
    f32x16 z = {0.f,0.f,0.f,0.f,0.f,0.f,0.f,0.f,
                0.f,0.f,0.f,0.f,0.f,0.f,0.f,0.f};
    return z;
}

// q pre-scale: log2(e) / sqrt(32)
#define QSCALE 0.25505392421795654f

// v_cvt_pk_bf16_f32: dst.lo = bf16(lo), dst.hi = bf16(hi)  (no builtin on gfx950)
#define CVT_PK(dst, lo, hi_) \
    asm("v_cvt_pk_bf16_f32 %0, %1, %2" : "=v"(dst) : "v"(lo), "v"(hi_))
// v_permlane32_swap_b32: x[32:63] <-> y[0:31]
#define PLSWAP(x, y) \
    asm("v_permlane32_swap_b32 %0, %1" : "+v"(x), "+v"(y))

// ---------------------------------------------------------------------------
// ROUND 19: attack latency-boundness (R18 counters: MfmaUtil 13.7%, VALU 32%,
// HBM 4.9%, Occ 37% -- NO pipe busy; grid capped occupancy at 16 waves/CU).
// attn_k goes to 512-thread blocks: 8 waves = qp{0,1} x seg{0..3}, each wave
// a QUARTER of the j range. Same grid (1024 blocks) -> 32 waves/CU theoretical,
// K/V L2 traffic unchanged (block still reads K+V exactly once). Loop body
// byte-identical to R18 (proven numerics); epilogue = 4-way additive combine.
// ---------------------------------------------------------------------------

// ---------------------------------------------------------------------------
// Kernel 0: f32 -> bf16 convert, both weight arrays in one launch.
// ---------------------------------------------------------------------------
__global__ __launch_bounds__(256) void convw_k(const float* __restrict__ s1,
                                               __bf16* __restrict__ d1, int n1,
                                               const float* __restrict__ s2,
                                               __bf16* __restrict__ d2, int n2) {
    const int i = blockIdx.x * 256 + threadIdx.x;
    if (i < n1) d1[i] = (__bf16)s1[i];
    else if (i - n1 < n2) d2[i - n1] = (__bf16)s2[i - n1];
}

// ---------------------------------------------------------------------------
// Kernel 1: LDS-tiled transpose+convert x f32 [b][c][n] -> xt bf16 [b][n][c].
// ---------------------------------------------------------------------------
__global__ __launch_bounds__(256) void transpose_k(const float* __restrict__ x,
                                                   __bf16* __restrict__ xt) {
    __shared__ __bf16 T[64][65];
    const int tid = threadIdx.x;
    const int n0 = blockIdx.x * 64, c0 = blockIdx.y * 64, b = blockIdx.z;

#pragma unroll
    for (int rep = 0; rep < 16; ++rep) {
        const int e = rep * 256 + tid;
        const int cl = e >> 6, nl = e & 63;
        T[nl][cl] = (__bf16)x[((size_t)(b * CC + c0 + cl)) * NT + n0 + nl];
    }
    __syncthreads();
#pragma unroll
    for (int rep = 0; rep < 16; ++rep) {
        const int e = rep * 256 + tid;
        const int nl = e >> 6, cl = e & 63;
        xt[((size_t)(b * NT + n0 + nl)) * CC + c0 + cl] = T[nl][cl];
    }
}

// ---------------------------------------------------------------------------
// Kernel 2: QKV GEMM (MFMA). q pre-scaled by QSCALE. Packed q/k stores.
// qt/kt token-major [bh][n][32], vv d-major [bh][32][n].
// grid (NT/64, 768/64, NB), block 256.
// ---------------------------------------------------------------------------
__global__ __launch_bounds__(256) void qkv_k(const __bf16* __restrict__ wqkv,
                                             const __bf16* __restrict__ xt,
                                             __bf16* __restrict__ qt,
                                             __bf16* __restrict__ kt,
                                             __bf16* __restrict__ vv) {
    const int lane = threadIdx.x & 63, wv = threadIdx.x >> 6;
    const int g = lane >> 4, c16 = lane & 15;
    const int b    = blockIdx.z;
    const int o0   = blockIdx.y * 64 + wv * 16;
    const int tok0 = blockIdx.x * 64;

    const __bf16* arow = wqkv + (size_t)(o0 + c16) * CC + g * 8;
    const __bf16* brow = xt + ((size_t)(b * NT + tok0 + c16)) * CC + g * 8;

    f32x4 acc[4];
#pragma unroll
    for (int i = 0; i < 4; ++i) acc[i] = zero4();

#pragma unroll
    for (int k0 = 0; k0 < CC; k0 += 32) {
        bf16x8 a = *(const bf16x8_ma*)(arow + k0);
#pragma unroll
        for (int js = 0; js < 4; ++js) {
            bf16x8 bb = *(const bf16x8_ma*)(brow + (size_t)js * 16 * CC + k0);
            acc[js] = __builtin_amdgcn_mfma_f32_16x16x32_bf16(a, bb, acc[js], 0, 0, 0);
        }
    }

    const int reg = o0 >> 8;                 // 0=q, 1=k, 2=v (wave-uniform)
    const int oo0 = (o0 & 255) + g * 4;
    const int h   = oo0 >> 5;
    const int dd0 = oo0 & 31;
    const size_t bh = (size_t)(b * NHD + h);

#pragma unroll
    for (int js = 0; js < 4; ++js) {
        const int tok = tok0 + js * 16 + c16;
        if (reg == 0) {
            bf16x4 pk;
#pragma unroll
            for (int r = 0; r < 4; ++r) pk[r] = (__bf16)(acc[js][r] * QSCALE);
            *(bf16x4_ma*)(qt + (bh * NT + tok) * HD + dd0) = pk;
        } else if (reg == 1) {
            bf16x4 pk;
#pragma unroll
            for (int r = 0; r < 4; ++r) pk[r] = (__bf16)acc[js][r];
            *(bf16x4_ma*)(kt + (bh * NT + tok) * HD + dd0) = pk;
        } else {
#pragma unroll
            for (int r = 0; r < 4; ++r)
                vv[(bh * HD + dd0 + r) * NT + tok] = (__bf16)acc[js][r];
        }
    }
}

// ---------------------------------------------------------------------------
// Kernel 3: MFMA flash attention, 32x32 swapped-operand, in-register P.
// Block 512 = 8 waves: (qp, seg), seg 0..3 = j-quarter. Wave owns 32 queries.
// Per 64-j tile: 4 K loads + 4 V loads (b128); 4 score MFMAs (S^T);
// 32 v_exp_f32; 32 f32 rs adds; 16 cvt_pk; 8 permlane32_swap; 4 PV MFMAs.
// Zero LDS ops in the loop. 4-way additive (O,l) combine in epilogue.
// grid (NT/64, NB*NHD), block 512 -> 4 blk/CU x 8 waves = 32 waves/CU.
// ---------------------------------------------------------------------------
__global__ __launch_bounds__(512, 8) void attn_k(const __bf16* __restrict__ qt,
                                                 const __bf16* __restrict__ kt,
                                                 const __bf16* __restrict__ vv,
                                                 __bf16* __restrict__ ao) {
    __shared__ __align__(16) float Olds[2][3][32][36];  // [qp][seg-1][d][q+pad] 27648 B
    __shared__ float llds[2][4][32];                    // [qp][seg][q]           1024 B

    const int tid  = threadIdx.x;
    const int lane = tid & 63, wv = tid >> 6;          // wv 0..7
    const int qp = wv & 1, seg = wv >> 1;              // seg 0..3
    const int c32 = lane & 31, hi = lane >> 5;
    const int bh = blockIdx.y;
    const int b = bh >> 3, h = bh & 7;
    const int i0 = blockIdx.x * 64 + qp * 32;          // this wave: 32 queries

    const __bf16* qbase = qt + ((size_t)bh * NT + i0) * HD;
    const __bf16* kbase = kt + (size_t)bh * NT * HD;
    const __bf16* vbase = vv + (size_t)bh * HD * NT;

    // Q fragments (B operand of score MFMA): row=q=c32, k = kk*16 + hi*8 + e
    bf16x8 aq0 = *(const bf16x8_ma*)(qbase + (size_t)c32 * HD + hi * 8);
    bf16x8 aq1 = *(const bf16x8_ma*)(qbase + (size_t)c32 * HD + 16 + hi * 8);

    f32x16 oacc = zero16();      // D[q_row][d_col]: rows=q, cols=d=c32
    float rs = 0.f;              // per-lane partial l for q = c32

    const int j_begin = seg * (NT / 4);
    const int j_end   = j_begin + (NT / 4);

    for (int j0 = j_begin; j0 < j_end; j0 += 64) {
#pragma unroll
        for (int js = 0; js < 2; ++js) {
            const int jb = j0 + js * 32;
            // K fragments (A operand): row=j=c32, k = kk*16 + hi*8 + e
            bf16x8 bk0 = *(const bf16x8_ma*)(kbase + (size_t)(jb + c32) * HD + hi * 8);
            bf16x8 bk1 = *(const bf16x8_ma*)(kbase + (size_t)(jb + c32) * HD + 16 + hi * 8);
            // V fragments (B operand of PV): row=d=c32, k = j offset
            bf16x8 bv0 = *(const bf16x8_ma*)(vbase + (size_t)c32 * NT + jb + hi * 8);
            bf16x8 bv1 = *(const bf16x8_ma*)(vbase + (size_t)c32 * NT + jb + 16 + hi * 8);

            // S^T tile [32 j][32 q]: lane holds j_row=(r&3)+8*(r>>2)+4*hi, q=c32
            f32x16 s = __builtin_amdgcn_mfma_f32_32x32x16_bf16(bk0, aq0, zero16(), 0, 0, 0);
            s = __builtin_amdgcn_mfma_f32_32x32x16_bf16(bk1, aq1, s, 0, 0, 0);

            // p = exp2(s) (q pre-scaled by log2e/sqrt(d)); rs accumulates in f32
            float p[16];
#pragma unroll
            for (int r = 0; r < 16; ++r) {
                p[r] = __builtin_amdgcn_exp2f(s[r]);
                rs += p[r];
            }

            // pack pairs: pk[i] = bf16(p[2i]) | bf16(p[2i+1])<<16
            unsigned pk[8];
#pragma unroll
            for (int i = 0; i < 8; ++i) CVT_PK(pk[i], p[2 * i], p[2 * i + 1]);

            // permlane32_swap redistribution (T12 pairing): after these 4 swaps
            // {pk0..3} is the PV A-frag for j [jb, jb+16), {pk4..7} for [jb+16, jb+32)
            PLSWAP(pk[0], pk[2]);
            PLSWAP(pk[1], pk[3]);
            PLSWAP(pk[4], pk[6]);
            PLSWAP(pk[5], pk[7]);

            u32x4 a0 = {pk[0], pk[1], pk[2], pk[3]};
            u32x4 a1 = {pk[4], pk[5], pk[6], pk[7]};
            const bf16x8 ap0 = __builtin_bit_cast(bf16x8, a0);
            const bf16x8 ap1 = __builtin_bit_cast(bf16x8, a1);

            oacc = __builtin_amdgcn_mfma_f32_32x32x16_bf16(ap0, bv0, oacc, 0, 0, 0);
            oacc = __builtin_amdgcn_mfma_f32_32x32x16_bf16(ap1, bv1, oacc, 0, 0, 0);
        }
    }

    // complete per-query l: lane and lane^32 each summed half the j's of q=c32
    rs += __shfl_xor(rs, 32, 64);

    if (hi == 0) llds[qp][seg][c32] = rs;
    if (seg > 0) {
        // O rows q = 8*g4 + 4*hi + (r&3): contiguous 4 -> f32x4 stores [d][q]
#pragma unroll
        for (int g4 = 0; g4 < 4; ++g4) {
            f32x4 t = {oacc[4 * g4 + 0], oacc[4 * g4 + 1],
                       oacc[4 * g4 + 2], oacc[4 * g4 + 3]};
            *(f32x4*)&Olds[qp][seg - 1][c32][8 * g4 + 4 * hi] = t;
        }
    }
    __syncthreads();
    if (seg == 0) {
#pragma unroll
        for (int g4 = 0; g4 < 4; ++g4) {
            const int q0 = 8 * g4 + 4 * hi;
            f32x4 osum = {oacc[4 * g4 + 0], oacc[4 * g4 + 1],
                          oacc[4 * g4 + 2], oacc[4 * g4 + 3]};
#pragma unroll
            for (int s = 0; s < 3; ++s)
                osum += *(const f32x4*)&Olds[qp][s][c32][q0];
#pragma unroll
            for (int r = 0; r < 4; ++r) {
                const int q = q0 + r;
                const float lt = llds[qp][0][q] + llds[qp][1][q] +
                                 llds[qp][2][q] + llds[qp][3][q];
                ao[((size_t)(b * NT) + i0 + q) * CC + h * HD + c32] =
                    (__bf16)(osum[r] / lt);
            }
        }
    }
}

// ---------------------------------------------------------------------------
// Kernel 4: proj GEMM + residual (MFMA), F32 output.
// grid (NT/64, CC/64, NB), block 256.
// ---------------------------------------------------------------------------
__global__ __launch_bounds__(256) void proj_k(const __bf16* __restrict__ wp,
                                              const __bf16* __restrict__ ao,
                                              const float* __restrict__ x,
                                              float* __restrict__ out) {
    const int lane = threadIdx.x & 63, wv = threadIdx.x >> 6;
    const int g = lane >> 4, c16 = lane & 15;
    const int b    = blockIdx.z;
    const int o0   = blockIdx.y * 64 + wv * 16;
    const int tok0 = blockIdx.x * 64;

    const __bf16* arow = wp + (size_t)(o0 + c16) * CC + g * 8;
    const __bf16* brow = ao + ((size_t)(b * NT + tok0 + c16)) * CC + g * 8;

    f32x4 acc[4];
#pragma unroll
    for (int i = 0; i < 4; ++i) acc[i] = zero4();

#pragma unroll
    for (int k0 = 0; k0 < CC; k0 += 32) {
        bf16x8 a = *(const bf16x8_ma*)(arow + k0);
#pragma unroll
        for (int js = 0; js < 4; ++js) {
            bf16x8 bb = *(const bf16x8_ma*)(brow + (size_t)js * 16 * CC + k0);
            acc[js] = __builtin_amdgcn_mfma_f32_16x16x32_bf16(a, bb, acc[js], 0, 0, 0);
        }
    }

#pragma unroll
    for (int js = 0; js < 4; ++js) {
        const int tok = tok0 + js * 16 + c16;
#pragma unroll
        for (int r = 0; r < 4; ++r) {
            const int o = o0 + g * 4 + r;
            const size_t idx = ((size_t)(b * CC + o)) * NT + tok;
            out[idx] = acc[js][r] + x[idx];
        }
    }
}

// ---------------------------------------------------------------------------
extern "C" void kernel_launch(void* const* d_in, const int* in_sizes, int n_in,
                              void* d_out, int out_size, void* d_ws, size_t ws_size,
                              hipStream_t stream) {
    const int SX  = NB * CC * NT;   // 2,097,152
    const int SW3 = 3 * CC * CC;    //   196,608
    const int SW1 = CC * CC;        //    65,536
    const size_t E = (size_t)SX;

    const float* x  = nullptr;
    const float* wq = nullptr;
    const float* wp = nullptr;
    for (int i = 0; i < n_in; ++i) {
        const int sz = in_sizes[i];
        if (sz == SX || sz == 2 * SX || sz == 4 * SX)           x  = (const float*)d_in[i];
        else if (sz == SW3 || sz == 2 * SW3 || sz == 4 * SW3)   wq = (const float*)d_in[i];
        else if (sz == SW1 || sz == 2 * SW1 || sz == 4 * SW1)   wp = (const float*)d_in[i];
    }
    if (!x || !wq || !wp) {
        x  = (const float*)d_in[0];
        wq = (const float*)d_in[1];
        wp = (const float*)d_in[2];
    }

    // Workspace (bf16 elements), 16.5 MB total (proven):
    __bf16* ws  = (__bf16*)d_ws;
    __bf16* wqb = ws;
    __bf16* wpb = wqb + SW3;
    __bf16* xt  = wpb + SW1;             // becomes ao after qkv_k
    __bf16* qt  = xt + E;
    __bf16* kt  = qt + E;
    __bf16* vv  = kt + E;
    __bf16* ao  = xt;

    float* out = (float*)d_out;

    convw_k<<<dim3((SW3 + SW1 + 255) / 256), 256, 0, stream>>>(wq, wqb, SW3, wp, wpb, SW1);
    transpose_k<<<dim3(NT / 64, CC / 64, NB), 256, 0, stream>>>(x, xt);
    qkv_k<<<dim3(NT / 64, (3 * CC) / 64, NB), 256, 0, stream>>>(wqb, xt, qt, kt, vv);
    attn_k<<<dim3(NT / 64, NB * NHD), 512, 0, stream>>>(qt, kt, vv, ao);
    proj_k<<<dim3(NT / 64, CC / 64, NB), 256, 0, stream>>>(wpb, ao, x, out);
}

// Round 3
// 198.155 us; speedup vs baseline: 1.3037x; 1.3037x over previous
//
#include <hip/hip_runtime.h>
#include <hip/hip_bf16.h>

// Problem constants
#define NB  2      // batch
#define CC  256    // channels
#define NHD 8      // heads
#define HD  32     // head dim
#define NT  4096   // tokens = H*W

typedef __bf16 bf16x8 __attribute__((ext_vector_type(8)));
typedef bf16x8 bf16x8_ma __attribute__((may_alias));
typedef __bf16 bf16x4 __attribute__((ext_vector_type(4)));
typedef bf16x4 bf16x4_ma __attribute__((may_alias));
typedef float  f32x4  __attribute__((ext_vector_type(4)));
typedef float  f32x16 __attribute__((ext_vector_type(16)));
typedef unsigned int u32x4 __attribute__((ext_vector_type(4)));

static __device__ __forceinline__ f32x4 zero4() {
    f32x4 z = {0.f, 0.f, 0.f, 0.f}; return z;
}
static __device__ __forceinline__ f32x16 zero16() {
    f32x16 z = {0.f,0.f,0.f,0.f,0.f,0.f,0.f,0.f,
                0.f,0.f,0.f,0.f,0.f,0.f,0.f,0.f};
    return z;
}

// q pre-scale: log2(e) / sqrt(32)
#define QSCALE 0.25505392421795654f

// v_cvt_pk_bf16_f32: dst.lo = bf16(lo), dst.hi = bf16(hi)  (no builtin on gfx950)
#define CVT_PK(dst, lo, hi_) \
    asm("v_cvt_pk_bf16_f32 %0, %1, %2" : "=v"(dst) : "v"(lo), "v"(hi_))
// v_permlane32_swap_b32: x[32:63] <-> y[0:31]
#define PLSWAP(x, y) \
    asm("v_permlane32_swap_b32 %0, %1" : "+v"(x), "+v"(y))

// ---------------------------------------------------------------------------
// ROUND 20: R19 post-mortem -- __launch_bounds__(512,8) forced a 64-VGPR
// budget, spilled (VGPR 40->32, WRITE_SIZE 4MB->108MB scratch). Occupancy was
// grid-capped, not register-capped. Fix: MORE BLOCKS, same proven block shape.
// attn_k: block = 32 queries x 4 waves (wave = j-quarter). Grid (NT/32, 16) =
// 2048 blocks = 8 blk/CU x 4 waves = 32 waves/CU theoretical. Loop body
// byte-identical to R18 (proven 40 VGPR, no spill). K/V per head = 512KB =
// L2-resident, so the 2x block-level K/V re-read is L2-absorbed.
// ---------------------------------------------------------------------------

// ---------------------------------------------------------------------------
// Kernel 0: f32 -> bf16 convert, both weight arrays in one launch.
// ---------------------------------------------------------------------------
__global__ __launch_bounds__(256) void convw_k(const float* __restrict__ s1,
                                               __bf16* __restrict__ d1, int n1,
                                               const float* __restrict__ s2,
                                               __bf16* __restrict__ d2, int n2) {
    const int i = blockIdx.x * 256 + threadIdx.x;
    if (i < n1) d1[i] = (__bf16)s1[i];
    else if (i - n1 < n2) d2[i - n1] = (__bf16)s2[i - n1];
}

// ---------------------------------------------------------------------------
// Kernel 1: LDS-tiled transpose+convert x f32 [b][c][n] -> xt bf16 [b][n][c].
// ---------------------------------------------------------------------------
__global__ __launch_bounds__(256) void transpose_k(const float* __restrict__ x,
                                                   __bf16* __restrict__ xt) {
    __shared__ __bf16 T[64][65];
    const int tid = threadIdx.x;
    const int n0 = blockIdx.x * 64, c0 = blockIdx.y * 64, b = blockIdx.z;

#pragma unroll
    for (int rep = 0; rep < 16; ++rep) {
        const int e = rep * 256 + tid;
        const int cl = e >> 6, nl = e & 63;
        T[nl][cl] = (__bf16)x[((size_t)(b * CC + c0 + cl)) * NT + n0 + nl];
    }
    __syncthreads();
#pragma unroll
    for (int rep = 0; rep < 16; ++rep) {
        const int e = rep * 256 + tid;
        const int nl = e >> 6, cl = e & 63;
        xt[((size_t)(b * NT + n0 + nl)) * CC + c0 + cl] = T[nl][cl];
    }
}

// ---------------------------------------------------------------------------
// Kernel 2: QKV GEMM (MFMA). q pre-scaled by QSCALE. Packed q/k stores.
// qt/kt token-major [bh][n][32], vv d-major [bh][32][n].
// grid (NT/64, 768/64, NB), block 256.
// ---------------------------------------------------------------------------
__global__ __launch_bounds__(256) void qkv_k(const __bf16* __restrict__ wqkv,
                                             const __bf16* __restrict__ xt,
                                             __bf16* __restrict__ qt,
                                             __bf16* __restrict__ kt,
                                             __bf16* __restrict__ vv) {
    const int lane = threadIdx.x & 63, wv = threadIdx.x >> 6;
    const int g = lane >> 4, c16 = lane & 15;
    const int b    = blockIdx.z;
    const int o0   = blockIdx.y * 64 + wv * 16;
    const int tok0 = blockIdx.x * 64;

    const __bf16* arow = wqkv + (size_t)(o0 + c16) * CC + g * 8;
    const __bf16* brow = xt + ((size_t)(b * NT + tok0 + c16)) * CC + g * 8;

    f32x4 acc[4];
#pragma unroll
    for (int i = 0; i < 4; ++i) acc[i] = zero4();

#pragma unroll
    for (int k0 = 0; k0 < CC; k0 += 32) {
        bf16x8 a = *(const bf16x8_ma*)(arow + k0);
#pragma unroll
        for (int js = 0; js < 4; ++js) {
            bf16x8 bb = *(const bf16x8_ma*)(brow + (size_t)js * 16 * CC + k0);
            acc[js] = __builtin_amdgcn_mfma_f32_16x16x32_bf16(a, bb, acc[js], 0, 0, 0);
        }
    }

    const int reg = o0 >> 8;                 // 0=q, 1=k, 2=v (wave-uniform)
    const int oo0 = (o0 & 255) + g * 4;
    const int h   = oo0 >> 5;
    const int dd0 = oo0 & 31;
    const size_t bh = (size_t)(b * NHD + h);

#pragma unroll
    for (int js = 0; js < 4; ++js) {
        const int tok = tok0 + js * 16 + c16;
        if (reg == 0) {
            bf16x4 pk;
#pragma unroll
            for (int r = 0; r < 4; ++r) pk[r] = (__bf16)(acc[js][r] * QSCALE);
            *(bf16x4_ma*)(qt + (bh * NT + tok) * HD + dd0) = pk;
        } else if (reg == 1) {
            bf16x4 pk;
#pragma unroll
            for (int r = 0; r < 4; ++r) pk[r] = (__bf16)acc[js][r];
            *(bf16x4_ma*)(kt + (bh * NT + tok) * HD + dd0) = pk;
        } else {
#pragma unroll
            for (int r = 0; r < 4; ++r)
                vv[(bh * HD + dd0 + r) * NT + tok] = (__bf16)acc[js][r];
        }
    }
}

// ---------------------------------------------------------------------------
// Kernel 3: MFMA flash attention, 32x32 swapped-operand, in-register P.
// Block 256 = 4 waves = 4 j-quarter segments; block owns 32 queries.
// Per 64-j tile: 4 K loads + 4 V loads (b128); 4 score MFMAs (S^T);
// 32 v_exp_f32; 32 f32 rs adds; 16 cvt_pk; 8 permlane32_swap; 4 PV MFMAs.
// Zero LDS ops in the loop. 4-way additive (O,l) combine in epilogue.
// grid (NT/32, NB*NHD) = 2048 blocks -> 8 blk/CU x 4 waves = 32 waves/CU.
// ---------------------------------------------------------------------------
__global__ __launch_bounds__(256, 4) void attn_k(const __bf16* __restrict__ qt,
                                                 const __bf16* __restrict__ kt,
                                                 const __bf16* __restrict__ vv,
                                                 __bf16* __restrict__ ao) {
    __shared__ __align__(16) float Olds[3][32][36];  // [seg-1][d][q+pad] 13824 B
    __shared__ float llds[4][32];                    // [seg][q]            512 B

    const int tid  = threadIdx.x;
    const int lane = tid & 63, seg = tid >> 6;         // seg 0..3 = j-quarter
    const int c32 = lane & 31, hi = lane >> 5;
    const int bh = blockIdx.y;
    const int b = bh >> 3, h = bh & 7;
    const int i0 = blockIdx.x * 32;                    // this block: 32 queries

    const __bf16* qbase = qt + ((size_t)bh * NT + i0) * HD;
    const __bf16* kbase = kt + (size_t)bh * NT * HD;
    const __bf16* vbase = vv + (size_t)bh * HD * NT;

    // Q fragments (B operand of score MFMA): row=q=c32, k = kk*16 + hi*8 + e
    bf16x8 aq0 = *(const bf16x8_ma*)(qbase + (size_t)c32 * HD + hi * 8);
    bf16x8 aq1 = *(const bf16x8_ma*)(qbase + (size_t)c32 * HD + 16 + hi * 8);

    f32x16 oacc = zero16();      // D[q_row][d_col]: rows=q, cols=d=c32
    float rs = 0.f;              // per-lane partial l for q = c32

    const int j_begin = seg * (NT / 4);
    const int j_end   = j_begin + (NT / 4);

    for (int j0 = j_begin; j0 < j_end; j0 += 64) {
#pragma unroll
        for (int js = 0; js < 2; ++js) {
            const int jb = j0 + js * 32;
            // K fragments (A operand): row=j=c32, k = kk*16 + hi*8 + e
            bf16x8 bk0 = *(const bf16x8_ma*)(kbase + (size_t)(jb + c32) * HD + hi * 8);
            bf16x8 bk1 = *(const bf16x8_ma*)(kbase + (size_t)(jb + c32) * HD + 16 + hi * 8);
            // V fragments (B operand of PV): row=d=c32, k = j offset
            bf16x8 bv0 = *(const bf16x8_ma*)(vbase + (size_t)c32 * NT + jb + hi * 8);
            bf16x8 bv1 = *(const bf16x8_ma*)(vbase + (size_t)c32 * NT + jb + 16 + hi * 8);

            // S^T tile [32 j][32 q]: lane holds j_row=(r&3)+8*(r>>2)+4*hi, q=c32
            f32x16 s = __builtin_amdgcn_mfma_f32_32x32x16_bf16(bk0, aq0, zero16(), 0, 0, 0);
            s = __builtin_amdgcn_mfma_f32_32x32x16_bf16(bk1, aq1, s, 0, 0, 0);

            // p = exp2(s) (q pre-scaled by log2e/sqrt(d)); rs accumulates in f32
            float p[16];
#pragma unroll
            for (int r = 0; r < 16; ++r) {
                p[r] = __builtin_amdgcn_exp2f(s[r]);
                rs += p[r];
            }

            // pack pairs: pk[i] = bf16(p[2i]) | bf16(p[2i+1])<<16
            unsigned pk[8];
#pragma unroll
            for (int i = 0; i < 8; ++i) CVT_PK(pk[i], p[2 * i], p[2 * i + 1]);

            // permlane32_swap redistribution (T12 pairing): after these 4 swaps
            // {pk0..3} is the PV A-frag for j [jb, jb+16), {pk4..7} for [jb+16, jb+32)
            PLSWAP(pk[0], pk[2]);
            PLSWAP(pk[1], pk[3]);
            PLSWAP(pk[4], pk[6]);
            PLSWAP(pk[5], pk[7]);

            u32x4 a0 = {pk[0], pk[1], pk[2], pk[3]};
            u32x4 a1 = {pk[4], pk[5], pk[6], pk[7]};
            const bf16x8 ap0 = __builtin_bit_cast(bf16x8, a0);
            const bf16x8 ap1 = __builtin_bit_cast(bf16x8, a1);

            oacc = __builtin_amdgcn_mfma_f32_32x32x16_bf16(ap0, bv0, oacc, 0, 0, 0);
            oacc = __builtin_amdgcn_mfma_f32_32x32x16_bf16(ap1, bv1, oacc, 0, 0, 0);
        }
    }

    // complete per-query l: lane and lane^32 each summed half the j's of q=c32
    rs += __shfl_xor(rs, 32, 64);

    if (hi == 0) llds[seg][c32] = rs;
    if (seg > 0) {
        // O rows q = 8*g4 + 4*hi + (r&3): contiguous 4 -> f32x4 stores [d][q]
#pragma unroll
        for (int g4 = 0; g4 < 4; ++g4) {
            f32x4 t = {oacc[4 * g4 + 0], oacc[4 * g4 + 1],
                       oacc[4 * g4 + 2], oacc[4 * g4 + 3]};
            *(f32x4*)&Olds[seg - 1][c32][8 * g4 + 4 * hi] = t;
        }
    }
    __syncthreads();
    if (seg == 0) {
#pragma unroll
        for (int g4 = 0; g4 < 4; ++g4) {
            const int q0 = 8 * g4 + 4 * hi;
            f32x4 osum = {oacc[4 * g4 + 0], oacc[4 * g4 + 1],
                          oacc[4 * g4 + 2], oacc[4 * g4 + 3]};
#pragma unroll
            for (int s = 0; s < 3; ++s)
                osum += *(const f32x4*)&Olds[s][c32][q0];
#pragma unroll
            for (int r = 0; r < 4; ++r) {
                const int q = q0 + r;
                const float lt = llds[0][q] + llds[1][q] +
                                 llds[2][q] + llds[3][q];
                ao[((size_t)(b * NT) + i0 + q) * CC + h * HD + c32] =
                    (__bf16)(osum[r] / lt);
            }
        }
    }
}

// ---------------------------------------------------------------------------
// Kernel 4: proj GEMM + residual (MFMA), F32 output.
// grid (NT/64, CC/64, NB), block 256.
// ---------------------------------------------------------------------------
__global__ __launch_bounds__(256) void proj_k(const __bf16* __restrict__ wp,
                                              const __bf16* __restrict__ ao,
                                              const float* __restrict__ x,
                                              float* __restrict__ out) {
    const int lane = threadIdx.x & 63, wv = threadIdx.x >> 6;
    const int g = lane >> 4, c16 = lane & 15;
    const int b    = blockIdx.z;
    const int o0   = blockIdx.y * 64 + wv * 16;
    const int tok0 = blockIdx.x * 64;

    const __bf16* arow = wp + (size_t)(o0 + c16) * CC + g * 8;
    const __bf16* brow = ao + ((size_t)(b * NT + tok0 + c16)) * CC + g * 8;

    f32x4 acc[4];
#pragma unroll
    for (int i = 0; i < 4; ++i) acc[i] = zero4();

#pragma unroll
    for (int k0 = 0; k0 < CC; k0 += 32) {
        bf16x8 a = *(const bf16x8_ma*)(arow + k0);
#pragma unroll
        for (int js = 0; js < 4; ++js) {
            bf16x8 bb = *(const bf16x8_ma*)(brow + (size_t)js * 16 * CC + k0);
            acc[js] = __builtin_amdgcn_mfma_f32_16x16x32_bf16(a, bb, acc[js], 0, 0, 0);
        }
    }

#pragma unroll
    for (int js = 0; js < 4; ++js) {
        const int tok = tok0 + js * 16 + c16;
#pragma unroll
        for (int r = 0; r < 4; ++r) {
            const int o = o0 + g * 4 + r;
            const size_t idx = ((size_t)(b * CC + o)) * NT + tok;
            out[idx] = acc[js][r] + x[idx];
        }
    }
}

// ---------------------------------------------------------------------------
extern "C" void kernel_launch(void* const* d_in, const int* in_sizes, int n_in,
                              void* d_out, int out_size, void* d_ws, size_t ws_size,
                              hipStream_t stream) {
    const int SX  = NB * CC * NT;   // 2,097,152
    const int SW3 = 3 * CC * CC;    //   196,608
    const int SW1 = CC * CC;        //    65,536
    const size_t E = (size_t)SX;

    const float* x  = nullptr;
    const float* wq = nullptr;
    const float* wp = nullptr;
    for (int i = 0; i < n_in; ++i) {
        const int sz = in_sizes[i];
        if (sz == SX || sz == 2 * SX || sz == 4 * SX)           x  = (const float*)d_in[i];
        else if (sz == SW3 || sz == 2 * SW3 || sz == 4 * SW3)   wq = (const float*)d_in[i];
        else if (sz == SW1 || sz == 2 * SW1 || sz == 4 * SW1)   wp = (const float*)d_in[i];
    }
    if (!x || !wq || !wp) {
        x  = (const float*)d_in[0];
        wq = (const float*)d_in[1];
        wp = (const float*)d_in[2];
    }

    // Workspace (bf16 elements), 16.5 MB total (proven):
    __bf16* ws  = (__bf16*)d_ws;
    __bf16* wqb = ws;
    __bf16* wpb = wqb + SW3;
    __bf16* xt  = wpb + SW1;             // becomes ao after qkv_k
    __bf16* qt  = xt + E;
    __bf16* kt  = qt + E;
    __bf16* vv  = kt + E;
    __bf16* ao  = xt;

    float* out = (float*)d_out;

    convw_k<<<dim3((SW3 + SW1 + 255) / 256), 256, 0, stream>>>(wq, wqb, SW3, wp, wpb, SW1);
    transpose_k<<<dim3(NT / 64, CC / 64, NB), 256, 0, stream>>>(x, xt);
    qkv_k<<<dim3(NT / 64, (3 * CC) / 64, NB), 256, 0, stream>>>(wqb, xt, qt, kt, vv);
    attn_k<<<dim3(NT / 32, NB * NHD), 256, 0, stream>>>(qt, kt, vv, ao);
    proj_k<<<dim3(NT / 64, CC / 64, NB), 256, 0, stream>>>(wpb, ao, x, out);
}

// Round 4
// 197.144 us; speedup vs baseline: 1.3104x; 1.0051x over previous
//
#include <hip/hip_runtime.h>
#include <hip/hip_bf16.h>

// Problem constants
#define NB  2      // batch
#define CC  256    // channels
#define NHD 8      // heads
#define HD  32     // head dim
#define NT  4096   // tokens = H*W

typedef __bf16 bf16x8 __attribute__((ext_vector_type(8)));
typedef bf16x8 bf16x8_ma __attribute__((may_alias));
typedef __bf16 bf16x4 __attribute__((ext_vector_type(4)));
typedef bf16x4 bf16x4_ma __attribute__((may_alias));
typedef float  f32x4  __attribute__((ext_vector_type(4)));
typedef float  f32x16 __attribute__((ext_vector_type(16)));
typedef unsigned int u32x4 __attribute__((ext_vector_type(4)));

static __device__ __forceinline__ f32x4 zero4() {
    f32x4 z = {0.f, 0.f, 0.f, 0.f}; return z;
}
static __device__ __forceinline__ f32x16 zero16() {
    f32x16 z = {0.f,0.f,0.f,0.f,0.f,0.f,0.f,0.f,
                0.f,0.f,0.f,0.f,0.f,0.f,0.f,0.f};
    return z;
}

// q pre-scale: log2(e) / sqrt(32)
#define QSCALE 0.25505392421795654f

// v_cvt_pk_bf16_f32: dst.lo = bf16(lo), dst.hi = bf16(hi)  (no builtin on gfx950)
#define CVT_PK(dst, lo, hi_) \
    asm("v_cvt_pk_bf16_f32 %0, %1, %2" : "=v"(dst) : "v"(lo), "v"(hi_))
// v_permlane32_swap_b32: x[32:63] <-> y[0:31]
#define PLSWAP(x, y) \
    asm("v_permlane32_swap_b32 %0, %1" : "+v"(x), "+v"(y))

// ---------------------------------------------------------------------------
// ROUND 21: R20 post-mortem -- occupancy 37->51% with ZERO speedup => waves
// were not scarce; each wave's chain is memory-latency-serialized. VGPR=40
// proves the compiler reuses the 8 load dest regs every sub-tile, so next
// loads can't issue until current compute drains (load ~300-600cy ON the
// critical path). Fix: T14 issue-early register double-buffer -- two named
// A/B buffer sets, LOADT(B); COMPUTE(A); LOADT(A+64); COMPUTE(B). Also split
// the 16-deep serial rs add chain into 4 accumulators. Math unchanged.
// ---------------------------------------------------------------------------

// ---------------------------------------------------------------------------
// Kernel 0: f32 -> bf16 convert, both weight arrays in one launch.
// ---------------------------------------------------------------------------
__global__ __launch_bounds__(256) void convw_k(const float* __restrict__ s1,
                                               __bf16* __restrict__ d1, int n1,
                                               const float* __restrict__ s2,
                                               __bf16* __restrict__ d2, int n2) {
    const int i = blockIdx.x * 256 + threadIdx.x;
    if (i < n1) d1[i] = (__bf16)s1[i];
    else if (i - n1 < n2) d2[i - n1] = (__bf16)s2[i - n1];
}

// ---------------------------------------------------------------------------
// Kernel 1: LDS-tiled transpose+convert x f32 [b][c][n] -> xt bf16 [b][n][c].
// ---------------------------------------------------------------------------
__global__ __launch_bounds__(256) void transpose_k(const float* __restrict__ x,
                                                   __bf16* __restrict__ xt) {
    __shared__ __bf16 T[64][65];
    const int tid = threadIdx.x;
    const int n0 = blockIdx.x * 64, c0 = blockIdx.y * 64, b = blockIdx.z;

#pragma unroll
    for (int rep = 0; rep < 16; ++rep) {
        const int e = rep * 256 + tid;
        const int cl = e >> 6, nl = e & 63;
        T[nl][cl] = (__bf16)x[((size_t)(b * CC + c0 + cl)) * NT + n0 + nl];
    }
    __syncthreads();
#pragma unroll
    for (int rep = 0; rep < 16; ++rep) {
        const int e = rep * 256 + tid;
        const int nl = e >> 6, cl = e & 63;
        xt[((size_t)(b * NT + n0 + nl)) * CC + c0 + cl] = T[nl][cl];
    }
}

// ---------------------------------------------------------------------------
// Kernel 2: QKV GEMM (MFMA). q pre-scaled by QSCALE. Packed q/k stores.
// qt/kt token-major [bh][n][32], vv d-major [bh][32][n].
// grid (NT/64, 768/64, NB), block 256.
// ---------------------------------------------------------------------------
__global__ __launch_bounds__(256) void qkv_k(const __bf16* __restrict__ wqkv,
                                             const __bf16* __restrict__ xt,
                                             __bf16* __restrict__ qt,
                                             __bf16* __restrict__ kt,
                                             __bf16* __restrict__ vv) {
    const int lane = threadIdx.x & 63, wv = threadIdx.x >> 6;
    const int g = lane >> 4, c16 = lane & 15;
    const int b    = blockIdx.z;
    const int o0   = blockIdx.y * 64 + wv * 16;
    const int tok0 = blockIdx.x * 64;

    const __bf16* arow = wqkv + (size_t)(o0 + c16) * CC + g * 8;
    const __bf16* brow = xt + ((size_t)(b * NT + tok0 + c16)) * CC + g * 8;

    f32x4 acc[4];
#pragma unroll
    for (int i = 0; i < 4; ++i) acc[i] = zero4();

#pragma unroll
    for (int k0 = 0; k0 < CC; k0 += 32) {
        bf16x8 a = *(const bf16x8_ma*)(arow + k0);
#pragma unroll
        for (int js = 0; js < 4; ++js) {
            bf16x8 bb = *(const bf16x8_ma*)(brow + (size_t)js * 16 * CC + k0);
            acc[js] = __builtin_amdgcn_mfma_f32_16x16x32_bf16(a, bb, acc[js], 0, 0, 0);
        }
    }

    const int reg = o0 >> 8;                 // 0=q, 1=k, 2=v (wave-uniform)
    const int oo0 = (o0 & 255) + g * 4;
    const int h   = oo0 >> 5;
    const int dd0 = oo0 & 31;
    const size_t bh = (size_t)(b * NHD + h);

#pragma unroll
    for (int js = 0; js < 4; ++js) {
        const int tok = tok0 + js * 16 + c16;
        if (reg == 0) {
            bf16x4 pk;
#pragma unroll
            for (int r = 0; r < 4; ++r) pk[r] = (__bf16)(acc[js][r] * QSCALE);
            *(bf16x4_ma*)(qt + (bh * NT + tok) * HD + dd0) = pk;
        } else if (reg == 1) {
            bf16x4 pk;
#pragma unroll
            for (int r = 0; r < 4; ++r) pk[r] = (__bf16)acc[js][r];
            *(bf16x4_ma*)(kt + (bh * NT + tok) * HD + dd0) = pk;
        } else {
#pragma unroll
            for (int r = 0; r < 4; ++r)
                vv[(bh * HD + dd0 + r) * NT + tok] = (__bf16)acc[js][r];
        }
    }
}

// ---------------------------------------------------------------------------
// Kernel 3: MFMA flash attention, 32x32 swapped-operand, in-register P,
// register-double-buffered K/V (T14 issue-early).
// Block 256 = 4 waves = 4 j-quarter segments; block owns 32 queries.
// Per 32-j sub-tile: 4 b128 loads (K pair + V pair) into the *other* buffer
// while this buffer computes: 2 score MFMAs, 16 exp2, 4x rs adds, 8 cvt_pk,
// 4 permlane32_swap, 2 PV MFMAs. Zero LDS ops in the loop.
// grid (NT/32, NB*NHD) = 2048 blocks.
// ---------------------------------------------------------------------------
__global__ __launch_bounds__(256, 4) void attn_k(const __bf16* __restrict__ qt,
                                                 const __bf16* __restrict__ kt,
                                                 const __bf16* __restrict__ vv,
                                                 __bf16* __restrict__ ao) {
    __shared__ __align__(16) float Olds[3][32][36];  // [seg-1][d][q+pad] 13824 B
    __shared__ float llds[4][32];                    // [seg][q]            512 B

    const int tid  = threadIdx.x;
    const int lane = tid & 63, seg = tid >> 6;         // seg 0..3 = j-quarter
    const int c32 = lane & 31, hi = lane >> 5;
    const int bh = blockIdx.y;
    const int b = bh >> 3, h = bh & 7;
    const int i0 = blockIdx.x * 32;                    // this block: 32 queries

    const __bf16* qbase = qt + ((size_t)bh * NT + i0) * HD;
    const __bf16* kbase = kt + (size_t)bh * NT * HD;
    const __bf16* vbase = vv + (size_t)bh * HD * NT;

    // Q fragments (B operand of score MFMA): row=q=c32, k = kk*16 + hi*8 + e
    bf16x8 aq0 = *(const bf16x8_ma*)(qbase + (size_t)c32 * HD + hi * 8);
    bf16x8 aq1 = *(const bf16x8_ma*)(qbase + (size_t)c32 * HD + 16 + hi * 8);

    f32x16 oacc = zero16();      // D[q_row][d_col]: rows=q, cols=d=c32
    float rsa[4] = {0.f, 0.f, 0.f, 0.f};   // 4 independent partial-l chains

    const int j_begin = seg * (NT / 4);

    // Two named register buffer sets for K/V sub-tiles (32 j's each).
    bf16x8 Ak0, Ak1, Av0, Av1;
    bf16x8 Bk0, Bk1, Bv0, Bv1;

#define LOADT(P, jb) do {                                                            \
    P##k0 = *(const bf16x8_ma*)(kbase + (size_t)((jb) + c32) * HD + hi * 8);         \
    P##k1 = *(const bf16x8_ma*)(kbase + (size_t)((jb) + c32) * HD + 16 + hi * 8);    \
    P##v0 = *(const bf16x8_ma*)(vbase + (size_t)c32 * NT + (jb) + hi * 8);           \
    P##v1 = *(const bf16x8_ma*)(vbase + (size_t)c32 * NT + (jb) + 16 + hi * 8);      \
} while (0)

#define COMPUTE(P) do {                                                              \
    f32x16 s = __builtin_amdgcn_mfma_f32_32x32x16_bf16(P##k0, aq0, zero16(), 0, 0, 0); \
    s = __builtin_amdgcn_mfma_f32_32x32x16_bf16(P##k1, aq1, s, 0, 0, 0);             \
    float p[16];                                                                     \
    _Pragma("unroll")                                                                \
    for (int r = 0; r < 16; ++r) {                                                   \
        p[r] = __builtin_amdgcn_exp2f(s[r]);                                         \
        rsa[r & 3] += p[r];                                                          \
    }                                                                                \
    unsigned pk[8];                                                                  \
    _Pragma("unroll")                                                                \
    for (int i = 0; i < 8; ++i) CVT_PK(pk[i], p[2 * i], p[2 * i + 1]);               \
    PLSWAP(pk[0], pk[2]);                                                            \
    PLSWAP(pk[1], pk[3]);                                                            \
    PLSWAP(pk[4], pk[6]);                                                            \
    PLSWAP(pk[5], pk[7]);                                                            \
    u32x4 a0 = {pk[0], pk[1], pk[2], pk[3]};                                         \
    u32x4 a1 = {pk[4], pk[5], pk[6], pk[7]};                                         \
    const bf16x8 ap0 = __builtin_bit_cast(bf16x8, a0);                               \
    const bf16x8 ap1 = __builtin_bit_cast(bf16x8, a1);                               \
    oacc = __builtin_amdgcn_mfma_f32_32x32x16_bf16(ap0, P##v0, oacc, 0, 0, 0);       \
    oacc = __builtin_amdgcn_mfma_f32_32x32x16_bf16(ap1, P##v1, oacc, 0, 0, 0);       \
} while (0)

    // 32 sub-tiles of 32 j's; software-pipelined rotation A/B.
    int jb = j_begin;
    LOADT(A, jb);
#pragma unroll 1
    for (int t = 0; t < 15; ++t) {
        LOADT(B, jb + 32);
        COMPUTE(A);                 // sub-tile jb
        LOADT(A, jb + 64);
        COMPUTE(B);                 // sub-tile jb+32
        jb += 64;
    }
    LOADT(B, jb + 32);
    COMPUTE(A);                     // sub-tile j_begin+960
    COMPUTE(B);                     // sub-tile j_begin+992

#undef LOADT
#undef COMPUTE

    float rs = (rsa[0] + rsa[1]) + (rsa[2] + rsa[3]);
    // complete per-query l: lane and lane^32 each summed half the j's of q=c32
    rs += __shfl_xor(rs, 32, 64);

    if (hi == 0) llds[seg][c32] = rs;
    if (seg > 0) {
        // O rows q = 8*g4 + 4*hi + (r&3): contiguous 4 -> f32x4 stores [d][q]
#pragma unroll
        for (int g4 = 0; g4 < 4; ++g4) {
            f32x4 t = {oacc[4 * g4 + 0], oacc[4 * g4 + 1],
                       oacc[4 * g4 + 2], oacc[4 * g4 + 3]};
            *(f32x4*)&Olds[seg - 1][c32][8 * g4 + 4 * hi] = t;
        }
    }
    __syncthreads();
    if (seg == 0) {
#pragma unroll
        for (int g4 = 0; g4 < 4; ++g4) {
            const int q0 = 8 * g4 + 4 * hi;
            f32x4 osum = {oacc[4 * g4 + 0], oacc[4 * g4 + 1],
                          oacc[4 * g4 + 2], oacc[4 * g4 + 3]};
#pragma unroll
            for (int s = 0; s < 3; ++s)
                osum += *(const f32x4*)&Olds[s][c32][q0];
#pragma unroll
            for (int r = 0; r < 4; ++r) {
                const int q = q0 + r;
                const float lt = llds[0][q] + llds[1][q] +
                                 llds[2][q] + llds[3][q];
                ao[((size_t)(b * NT) + i0 + q) * CC + h * HD + c32] =
                    (__bf16)(osum[r] / lt);
            }
        }
    }
}

// ---------------------------------------------------------------------------
// Kernel 4: proj GEMM + residual (MFMA), F32 output.
// grid (NT/64, CC/64, NB), block 256.
// ---------------------------------------------------------------------------
__global__ __launch_bounds__(256) void proj_k(const __bf16* __restrict__ wp,
                                              const __bf16* __restrict__ ao,
                                              const float* __restrict__ x,
                                              float* __restrict__ out) {
    const int lane = threadIdx.x & 63, wv = threadIdx.x >> 6;
    const int g = lane >> 4, c16 = lane & 15;
    const int b    = blockIdx.z;
    const int o0   = blockIdx.y * 64 + wv * 16;
    const int tok0 = blockIdx.x * 64;

    const __bf16* arow = wp + (size_t)(o0 + c16) * CC + g * 8;
    const __bf16* brow = ao + ((size_t)(b * NT + tok0 + c16)) * CC + g * 8;

    f32x4 acc[4];
#pragma unroll
    for (int i = 0; i < 4; ++i) acc[i] = zero4();

#pragma unroll
    for (int k0 = 0; k0 < CC; k0 += 32) {
        bf16x8 a = *(const bf16x8_ma*)(arow + k0);
#pragma unroll
        for (int js = 0; js < 4; ++js) {
            bf16x8 bb = *(const bf16x8_ma*)(brow + (size_t)js * 16 * CC + k0);
            acc[js] = __builtin_amdgcn_mfma_f32_16x16x32_bf16(a, bb, acc[js], 0, 0, 0);
        }
    }

#pragma unroll
    for (int js = 0; js < 4; ++js) {
        const int tok = tok0 + js * 16 + c16;
#pragma unroll
        for (int r = 0; r < 4; ++r) {
            const int o = o0 + g * 4 + r;
            const size_t idx = ((size_t)(b * CC + o)) * NT + tok;
            out[idx] = acc[js][r] + x[idx];
        }
    }
}

// ---------------------------------------------------------------------------
extern "C" void kernel_launch(void* const* d_in, const int* in_sizes, int n_in,
                              void* d_out, int out_size, void* d_ws, size_t ws_size,
                              hipStream_t stream) {
    const int SX  = NB * CC * NT;   // 2,097,152
    const int SW3 = 3 * CC * CC;    //   196,608
    const int SW1 = CC * CC;        //    65,536
    const size_t E = (size_t)SX;

    const float* x  = nullptr;
    const float* wq = nullptr;
    const float* wp = nullptr;
    for (int i = 0; i < n_in; ++i) {
        const int sz = in_sizes[i];
        if (sz == SX || sz == 2 * SX || sz == 4 * SX)           x  = (const float*)d_in[i];
        else if (sz == SW3 || sz == 2 * SW3 || sz == 4 * SW3)   wq = (const float*)d_in[i];
        else if (sz == SW1 || sz == 2 * SW1 || sz == 4 * SW1)   wp = (const float*)d_in[i];
    }
    if (!x || !wq || !wp) {
        x  = (const float*)d_in[0];
        wq = (const float*)d_in[1];
        wp = (const float*)d_in[2];
    }

    // Workspace (bf16 elements), 16.5 MB total (proven):
    __bf16* ws  = (__bf16*)d_ws;
    __bf16* wqb = ws;
    __bf16* wpb = wqb + SW3;
    __bf16* xt  = wpb + SW1;             // becomes ao after qkv_k
    __bf16* qt  = xt + E;
    __bf16* kt  = qt + E;
    __bf16* vv  = kt + E;
    __bf16* ao  = xt;

    float* out = (float*)d_out;

    convw_k<<<dim3((SW3 + SW1 + 255) / 256), 256, 0, stream>>>(wq, wqb, SW3, wp, wpb, SW1);
    transpose_k<<<dim3(NT / 64, CC / 64, NB), 256, 0, stream>>>(x, xt);
    qkv_k<<<dim3(NT / 64, (3 * CC) / 64, NB), 256, 0, stream>>>(wqb, xt, qt, kt, vv);
    attn_k<<<dim3(NT / 32, NB * NHD), 256, 0, stream>>>(qt, kt, vv, ao);
    proj_k<<<dim3(NT / 64, CC / 64, NB), 256, 0, stream>>>(wpb, ao, x, out);
}

// Round 5
// 166.507 us; speedup vs baseline: 1.5515x; 1.1840x over previous
//
#include <hip/hip_runtime.h>
#include <hip/hip_bf16.h>

// Problem constants
#define NB  2      // batch
#define CC  256    // channels
#define NHD 8      // heads
#define HD  32     // head dim
#define NT  4096   // tokens = H*W

typedef __bf16 bf16x8 __attribute__((ext_vector_type(8)));
typedef bf16x8 bf16x8_ma __attribute__((may_alias));
typedef __bf16 bf16x4 __attribute__((ext_vector_type(4)));
typedef bf16x4 bf16x4_ma __attribute__((may_alias));
typedef float  f32x4  __attribute__((ext_vector_type(4)));
typedef float  f32x16 __attribute__((ext_vector_type(16)));
typedef unsigned int u32x4 __attribute__((ext_vector_type(4)));

static __device__ __forceinline__ f32x4 zero4() {
    f32x4 z = {0.f, 0.f, 0.f, 0.f}; return z;
}
static __device__ __forceinline__ f32x16 zero16() {
    f32x16 z = {0.f,0.f,0.f,0.f,0.f,0.f,0.f,0.f,
                0.f,0.f,0.f,0.f,0.f,0.f,0.f,0.f};
    return z;
}

// q pre-scale: log2(e) / sqrt(32)
#define QSCALE 0.25505392421795654f

// v_cvt_pk_bf16_f32: dst.lo = bf16(lo), dst.hi = bf16(hi)  (no builtin on gfx950)
#define CVT_PK(dst, lo, hi_) \
    asm("v_cvt_pk_bf16_f32 %0, %1, %2" : "=v"(dst) : "v"(lo), "v"(hi_))
// v_permlane32_swap_b32: x[32:63] <-> y[0:31]
#define PLSWAP(x, y) \
    asm("v_permlane32_swap_b32 %0, %1" : "+v"(x), "+v"(y))

// ---------------------------------------------------------------------------
// ROUND 22: R19-R21 all neutral at ~102us with every pipe idle; R20 (51% occ)
// == R21 (37% occ) => a SHARED resource saturates: L1/L2 cache-line request
// throughput (~25M line-requests / 16 lines/cy/XCD ~ 82us). Fix: 4x fewer
// line requests by sharing K/V across 128 queries per block. Block = 4 waves
// x 32q, ALL waves sweep the full j range; K/V tiles staged to LDS once per
// block via global_load_lds (fragment lane-order layout -> linear ds_read,
// no swizzle, no conflicts), double-buffered, 2-phase schedule. Epilogue
// seg-combine GONE (each wave owns complete rows). Subtile math = proven R21.
// grid (NT/128, NB*NHD) = 512 blocks, 2 blocks/CU, LDS 16KB.
// ---------------------------------------------------------------------------

// ---------------------------------------------------------------------------
// Kernel 0: f32 -> bf16 convert, both weight arrays in one launch.
// ---------------------------------------------------------------------------
__global__ __launch_bounds__(256) void convw_k(const float* __restrict__ s1,
                                               __bf16* __restrict__ d1, int n1,
                                               const float* __restrict__ s2,
                                               __bf16* __restrict__ d2, int n2) {
    const int i = blockIdx.x * 256 + threadIdx.x;
    if (i < n1) d1[i] = (__bf16)s1[i];
    else if (i - n1 < n2) d2[i - n1] = (__bf16)s2[i - n1];
}

// ---------------------------------------------------------------------------
// Kernel 1: LDS-tiled transpose+convert x f32 [b][c][n] -> xt bf16 [b][n][c].
// ---------------------------------------------------------------------------
__global__ __launch_bounds__(256) void transpose_k(const float* __restrict__ x,
                                                   __bf16* __restrict__ xt) {
    __shared__ __bf16 T[64][65];
    const int tid = threadIdx.x;
    const int n0 = blockIdx.x * 64, c0 = blockIdx.y * 64, b = blockIdx.z;

#pragma unroll
    for (int rep = 0; rep < 16; ++rep) {
        const int e = rep * 256 + tid;
        const int cl = e >> 6, nl = e & 63;
        T[nl][cl] = (__bf16)x[((size_t)(b * CC + c0 + cl)) * NT + n0 + nl];
    }
    __syncthreads();
#pragma unroll
    for (int rep = 0; rep < 16; ++rep) {
        const int e = rep * 256 + tid;
        const int nl = e >> 6, cl = e & 63;
        xt[((size_t)(b * NT + n0 + nl)) * CC + c0 + cl] = T[nl][cl];
    }
}

// ---------------------------------------------------------------------------
// Kernel 2: QKV GEMM (MFMA). q pre-scaled by QSCALE. Packed q/k stores.
// qt/kt token-major [bh][n][32], vv d-major [bh][32][n].
// grid (NT/64, 768/64, NB), block 256.
// ---------------------------------------------------------------------------
__global__ __launch_bounds__(256) void qkv_k(const __bf16* __restrict__ wqkv,
                                             const __bf16* __restrict__ xt,
                                             __bf16* __restrict__ qt,
                                             __bf16* __restrict__ kt,
                                             __bf16* __restrict__ vv) {
    const int lane = threadIdx.x & 63, wv = threadIdx.x >> 6;
    const int g = lane >> 4, c16 = lane & 15;
    const int b    = blockIdx.z;
    const int o0   = blockIdx.y * 64 + wv * 16;
    const int tok0 = blockIdx.x * 64;

    const __bf16* arow = wqkv + (size_t)(o0 + c16) * CC + g * 8;
    const __bf16* brow = xt + ((size_t)(b * NT + tok0 + c16)) * CC + g * 8;

    f32x4 acc[4];
#pragma unroll
    for (int i = 0; i < 4; ++i) acc[i] = zero4();

#pragma unroll
    for (int k0 = 0; k0 < CC; k0 += 32) {
        bf16x8 a = *(const bf16x8_ma*)(arow + k0);
#pragma unroll
        for (int js = 0; js < 4; ++js) {
            bf16x8 bb = *(const bf16x8_ma*)(brow + (size_t)js * 16 * CC + k0);
            acc[js] = __builtin_amdgcn_mfma_f32_16x16x32_bf16(a, bb, acc[js], 0, 0, 0);
        }
    }

    const int reg = o0 >> 8;                 // 0=q, 1=k, 2=v (wave-uniform)
    const int oo0 = (o0 & 255) + g * 4;
    const int h   = oo0 >> 5;
    const int dd0 = oo0 & 31;
    const size_t bh = (size_t)(b * NHD + h);

#pragma unroll
    for (int js = 0; js < 4; ++js) {
        const int tok = tok0 + js * 16 + c16;
        if (reg == 0) {
            bf16x4 pk;
#pragma unroll
            for (int r = 0; r < 4; ++r) pk[r] = (__bf16)(acc[js][r] * QSCALE);
            *(bf16x4_ma*)(qt + (bh * NT + tok) * HD + dd0) = pk;
        } else if (reg == 1) {
            bf16x4 pk;
#pragma unroll
            for (int r = 0; r < 4; ++r) pk[r] = (__bf16)acc[js][r];
            *(bf16x4_ma*)(kt + (bh * NT + tok) * HD + dd0) = pk;
        } else {
#pragma unroll
            for (int r = 0; r < 4; ++r)
                vv[(bh * HD + dd0 + r) * NT + tok] = (__bf16)acc[js][r];
        }
    }
}

// ---------------------------------------------------------------------------
// Kernel 3: MFMA flash attention, 32x32 swapped-operand, in-register P,
// block-shared LDS K/V (global_load_lds, fragment lane-order, double-buffer).
// Block 256 thr = 4 waves x 32 queries = 128 q/block; all waves sweep full j.
// Per 64-j tile: 8 global_load_lds (2/wave) stage next tile; each wave does
// 2 subtiles: 4 ds_read_b128 (linear, conflict-free) + 2 score MFMAs + 16
// exp2 + 8 cvt_pk + 4 permlane + 2 PV MFMAs. One vmcnt(0)+barrier per tile.
// No cross-wave combine: each wave owns complete rows -> epilogue is direct.
// grid (NT/128, NB*NHD) = 512 blocks, LDS 16KB, 2 blocks/CU.
// ---------------------------------------------------------------------------
__global__ __launch_bounds__(256, 2) void attn_k(const __bf16* __restrict__ qt,
                                                 const __bf16* __restrict__ kt,
                                                 const __bf16* __restrict__ vv,
                                                 __bf16* __restrict__ ao) {
    // Fragment lane-order tiles: [buf][js][half][lane*8 bf16]
    __shared__ __align__(16) __bf16 KF[2][2][2][512];   // 8 KB
    __shared__ __align__(16) __bf16 VF[2][2][2][512];   // 8 KB

    const int tid  = threadIdx.x;
    const int lane = tid & 63, wv = tid >> 6;          // wv 0..3
    const int c32 = lane & 31, hi = lane >> 5;
    const int bh = blockIdx.y;
    const int b = bh >> 3, h = bh & 7;
    const int i0q = blockIdx.x * 128 + wv * 32;        // this wave: 32 queries

    const __bf16* qbase = qt + ((size_t)bh * NT + i0q) * HD;
    const __bf16* kbase = kt + (size_t)bh * NT * HD;
    const __bf16* vbase = vv + (size_t)bh * HD * NT;

    // Staging role of this wave: K chunk (stg_js, kk=stg_sl), V chunk (stg_js, vslot=stg_sl)
    const int stg_js = wv & 1, stg_sl = wv >> 1;

    // Q fragments (B operand of score MFMA): row=q=c32, k = kk*16 + hi*8 + e
    bf16x8 aq0 = *(const bf16x8_ma*)(qbase + (size_t)c32 * HD + hi * 8);
    bf16x8 aq1 = *(const bf16x8_ma*)(qbase + (size_t)c32 * HD + 16 + hi * 8);

    f32x16 oacc = zero16();      // D[q_row][d_col]: rows=q, cols=d=c32
    float rsa[4] = {0.f, 0.f, 0.f, 0.f};   // 4 independent partial-l chains

#define STAGE(bf, jb) do {                                                              \
    const __bf16* gk = kbase + (size_t)((jb) + stg_js * 32 + c32) * HD                  \
                             + stg_sl * 16 + hi * 8;                                    \
    __builtin_amdgcn_global_load_lds(                                                   \
        (const __attribute__((address_space(1))) void*)gk,                              \
        (__attribute__((address_space(3))) void*)&KF[bf][stg_js][stg_sl][0],            \
        16, 0, 0);                                                                      \
    const __bf16* gv = vbase + (size_t)c32 * NT + (jb) + stg_js * 32                    \
                             + stg_sl * 16 + hi * 8;                                    \
    __builtin_amdgcn_global_load_lds(                                                   \
        (const __attribute__((address_space(1))) void*)gv,                              \
        (__attribute__((address_space(3))) void*)&VF[bf][stg_js][stg_sl][0],            \
        16, 0, 0);                                                                      \
} while (0)

#define SUBTILE(bf, js) do {                                                            \
    bf16x8 fk0 = *(const bf16x8_ma*)&KF[bf][js][0][lane * 8];                           \
    bf16x8 fk1 = *(const bf16x8_ma*)&KF[bf][js][1][lane * 8];                           \
    bf16x8 fv0 = *(const bf16x8_ma*)&VF[bf][js][0][lane * 8];                           \
    bf16x8 fv1 = *(const bf16x8_ma*)&VF[bf][js][1][lane * 8];                           \
    f32x16 s = __builtin_amdgcn_mfma_f32_32x32x16_bf16(fk0, aq0, zero16(), 0, 0, 0);    \
    s = __builtin_amdgcn_mfma_f32_32x32x16_bf16(fk1, aq1, s, 0, 0, 0);                  \
    float p[16];                                                                        \
    _Pragma("unroll")                                                                   \
    for (int r = 0; r < 16; ++r) {                                                      \
        p[r] = __builtin_amdgcn_exp2f(s[r]);                                            \
        rsa[r & 3] += p[r];                                                             \
    }                                                                                   \
    unsigned pk[8];                                                                     \
    _Pragma("unroll")                                                                   \
    for (int i = 0; i < 8; ++i) CVT_PK(pk[i], p[2 * i], p[2 * i + 1]);                  \
    PLSWAP(pk[0], pk[2]);                                                               \
    PLSWAP(pk[1], pk[3]);                                                               \
    PLSWAP(pk[4], pk[6]);                                                               \
    PLSWAP(pk[5], pk[7]);                                                               \
    u32x4 a0 = {pk[0], pk[1], pk[2], pk[3]};                                            \
    u32x4 a1 = {pk[4], pk[5], pk[6], pk[7]};                                            \
    const bf16x8 ap0 = __builtin_bit_cast(bf16x8, a0);                                  \
    const bf16x8 ap1 = __builtin_bit_cast(bf16x8, a1);                                  \
    oacc = __builtin_amdgcn_mfma_f32_32x32x16_bf16(ap0, fv0, oacc, 0, 0, 0);            \
    oacc = __builtin_amdgcn_mfma_f32_32x32x16_bf16(ap1, fv1, oacc, 0, 0, 0);            \
} while (0)

    const int NTILES = NT / 64;   // 64

    // Prologue: stage tile 0 into buf 0.
    STAGE(0, 0);
    asm volatile("s_waitcnt vmcnt(0)" ::: "memory");
    __syncthreads();

    int buf = 0;
#pragma unroll 1
    for (int t = 0; t < NTILES; ++t) {
        if (t + 1 < NTILES) STAGE(buf ^ 1, (t + 1) * 64);
        SUBTILE(buf, 0);
        SUBTILE(buf, 1);
        asm volatile("s_waitcnt vmcnt(0)" ::: "memory");
        __syncthreads();
        buf ^= 1;
    }

#undef STAGE
#undef SUBTILE

    float rs = (rsa[0] + rsa[1]) + (rsa[2] + rsa[3]);
    // complete per-query l: lane and lane^32 each summed half the j's of q=c32
    rs += __shfl_xor(rs, 32, 64);

    // Direct epilogue: oacc rows q = 8*g4 + 4*hi + r, cols d = c32.
#pragma unroll
    for (int g4 = 0; g4 < 4; ++g4) {
#pragma unroll
        for (int r = 0; r < 4; ++r) {
            const int q = 8 * g4 + 4 * hi + r;
            const float lt = __shfl(rs, q, 64);
            ao[((size_t)(b * NT) + i0q + q) * CC + h * HD + c32] =
                (__bf16)(oacc[4 * g4 + r] / lt);
        }
    }
}

// ---------------------------------------------------------------------------
// Kernel 4: proj GEMM + residual (MFMA), F32 output.
// grid (NT/64, CC/64, NB), block 256.
// ---------------------------------------------------------------------------
__global__ __launch_bounds__(256) void proj_k(const __bf16* __restrict__ wp,
                                              const __bf16* __restrict__ ao,
                                              const float* __restrict__ x,
                                              float* __restrict__ out) {
    const int lane = threadIdx.x & 63, wv = threadIdx.x >> 6;
    const int g = lane >> 4, c16 = lane & 15;
    const int b    = blockIdx.z;
    const int o0   = blockIdx.y * 64 + wv * 16;
    const int tok0 = blockIdx.x * 64;

    const __bf16* arow = wp + (size_t)(o0 + c16) * CC + g * 8;
    const __bf16* brow = ao + ((size_t)(b * NT + tok0 + c16)) * CC + g * 8;

    f32x4 acc[4];
#pragma unroll
    for (int i = 0; i < 4; ++i) acc[i] = zero4();

#pragma unroll
    for (int k0 = 0; k0 < CC; k0 += 32) {
        bf16x8 a = *(const bf16x8_ma*)(arow + k0);
#pragma unroll
        for (int js = 0; js < 4; ++js) {
            bf16x8 bb = *(const bf16x8_ma*)(brow + (size_t)js * 16 * CC + k0);
            acc[js] = __builtin_amdgcn_mfma_f32_16x16x32_bf16(a, bb, acc[js], 0, 0, 0);
        }
    }

#pragma unroll
    for (int js = 0; js < 4; ++js) {
        const int tok = tok0 + js * 16 + c16;
#pragma unroll
        for (int r = 0; r < 4; ++r) {
            const int o = o0 + g * 4 + r;
            const size_t idx = ((size_t)(b * CC + o)) * NT + tok;
            out[idx] = acc[js][r] + x[idx];
        }
    }
}

// ---------------------------------------------------------------------------
extern "C" void kernel_launch(void* const* d_in, const int* in_sizes, int n_in,
                              void* d_out, int out_size, void* d_ws, size_t ws_size,
                              hipStream_t stream) {
    const int SX  = NB * CC * NT;   // 2,097,152
    const int SW3 = 3 * CC * CC;    //   196,608
    const int SW1 = CC * CC;        //    65,536
    const size_t E = (size_t)SX;

    const float* x  = nullptr;
    const float* wq = nullptr;
    const float* wp = nullptr;
    for (int i = 0; i < n_in; ++i) {
        const int sz = in_sizes[i];
        if (sz == SX || sz == 2 * SX || sz == 4 * SX)           x  = (const float*)d_in[i];
        else if (sz == SW3 || sz == 2 * SW3 || sz == 4 * SW3)   wq = (const float*)d_in[i];
        else if (sz == SW1 || sz == 2 * SW1 || sz == 4 * SW1)   wp = (const float*)d_in[i];
    }
    if (!x || !wq || !wp) {
        x  = (const float*)d_in[0];
        wq = (const float*)d_in[1];
        wp = (const float*)d_in[2];
    }

    // Workspace (bf16 elements), 16.5 MB total (proven):
    __bf16* ws  = (__bf16*)d_ws;
    __bf16* wqb = ws;
    __bf16* wpb = wqb + SW3;
    __bf16* xt  = wpb + SW1;             // becomes ao after qkv_k
    __bf16* qt  = xt + E;
    __bf16* kt  = qt + E;
    __bf16* vv  = kt + E;
    __bf16* ao  = xt;

    float* out = (float*)d_out;

    convw_k<<<dim3((SW3 + SW1 + 255) / 256), 256, 0, stream>>>(wq, wqb, SW3, wp, wpb, SW1);
    transpose_k<<<dim3(NT / 64, CC / 64, NB), 256, 0, stream>>>(x, xt);
    qkv_k<<<dim3(NT / 64, (3 * CC) / 64, NB), 256, 0, stream>>>(wqb, xt, qt, kt, vv);
    attn_k<<<dim3(NT / 128, NB * NHD), 256, 0, stream>>>(qt, kt, vv, ao);
    proj_k<<<dim3(NT / 64, CC / 64, NB), 256, 0, stream>>>(wpb, ao, x, out);
}

// Round 7
// 151.685 us; speedup vs baseline: 1.7031x; 1.0977x over previous
//
#include <hip/hip_runtime.h>
#include <hip/hip_bf16.h>

// Problem constants
#define NB  2      // batch
#define CC  256    // channels
#define NHD 8      // heads
#define HD  32     // head dim
#define NT  4096   // tokens = H*W

typedef __bf16 bf16x8 __attribute__((ext_vector_type(8)));
typedef bf16x8 bf16x8_ma __attribute__((may_alias));
typedef __bf16 bf16x4 __attribute__((ext_vector_type(4)));
typedef bf16x4 bf16x4_ma __attribute__((may_alias));
typedef float  f32x4  __attribute__((ext_vector_type(4)));
typedef float  f32x16 __attribute__((ext_vector_type(16)));
typedef unsigned int u32x4 __attribute__((ext_vector_type(4)));

static __device__ __forceinline__ f32x4 zero4() {
    f32x4 z = {0.f, 0.f, 0.f, 0.f}; return z;
}
static __device__ __forceinline__ f32x16 zero16() {
    f32x16 z = {0.f,0.f,0.f,0.f,0.f,0.f,0.f,0.f,
                0.f,0.f,0.f,0.f,0.f,0.f,0.f,0.f};
    return z;
}

// q pre-scale: log2(e) / sqrt(32)
#define QSCALE 0.25505392421795654f

// v_cvt_pk_bf16_f32: dst.lo = bf16(lo), dst.hi = bf16(hi)  (no builtin on gfx950)
#define CVT_PK(dst, lo, hi_) \
    asm("v_cvt_pk_bf16_f32 %0, %1, %2" : "=v"(dst) : "v"(lo), "v"(hi_))
// v_permlane32_swap_b32: x[32:63] <-> y[0:31]
#define PLSWAP(x, y) \
    asm("v_permlane32_swap_b32 %0, %1" : "+v"(x), "+v"(y))

// ---------------------------------------------------------------------------
// ROUND 24: R23 resubmit, hardened. R23's bench died at container level (no
// counters). Only defect found in audit: hipcc may sink register-only MFMAs
// past the inline-asm s_barrier (rule #18 family -- "memory" clobber does not
// order register math), letting tile t-1's pending ds_reads race the STAGE
// that overwrites its buffer. Fix: sched_barrier(0) pins program order at
// every TILE_WAIT. Design otherwise identical to R23:
//  (1) attn_k: counted-vmcnt 4-buffer pipeline (T3/T4), raw s_barrier,
//      vmcnt(4) steady state, setprio around MFMA cluster (T5).
//  (2) qkv_k/proj_k: block-shared B-tile staged once to LDS (R22 mechanism).
// ---------------------------------------------------------------------------

// ---------------------------------------------------------------------------
// Kernel 0: f32 -> bf16 convert, both weight arrays in one launch.
// ---------------------------------------------------------------------------
__global__ __launch_bounds__(256) void convw_k(const float* __restrict__ s1,
                                               __bf16* __restrict__ d1, int n1,
                                               const float* __restrict__ s2,
                                               __bf16* __restrict__ d2, int n2) {
    const int i = blockIdx.x * 256 + threadIdx.x;
    if (i < n1) d1[i] = (__bf16)s1[i];
    else if (i - n1 < n2) d2[i - n1] = (__bf16)s2[i - n1];
}

// ---------------------------------------------------------------------------
// Kernel 1: LDS-tiled transpose+convert x f32 [b][c][n] -> xt bf16 [b][n][c].
// ---------------------------------------------------------------------------
__global__ __launch_bounds__(256) void transpose_k(const float* __restrict__ x,
                                                   __bf16* __restrict__ xt) {
    __shared__ __bf16 T[64][65];
    const int tid = threadIdx.x;
    const int n0 = blockIdx.x * 64, c0 = blockIdx.y * 64, b = blockIdx.z;

#pragma unroll
    for (int rep = 0; rep < 16; ++rep) {
        const int e = rep * 256 + tid;
        const int cl = e >> 6, nl = e & 63;
        T[nl][cl] = (__bf16)x[((size_t)(b * CC + c0 + cl)) * NT + n0 + nl];
    }
    __syncthreads();
#pragma unroll
    for (int rep = 0; rep < 16; ++rep) {
        const int e = rep * 256 + tid;
        const int nl = e >> 6, cl = e & 63;
        xt[((size_t)(b * NT + n0 + nl)) * CC + c0 + cl] = T[nl][cl];
    }
}

// ---------------------------------------------------------------------------
// Kernel 2: QKV GEMM (MFMA), B-tile LDS-shared.
// Block = 64 o x 64 tok. The 32 KB B-tile (xt rows) is staged ONCE per block
// via global_load_lds in fragment lane-order; all 4 waves + all 8 k-iters
// read it from LDS. A (weights) preloaded into 8 regs during the stage.
// qt/kt token-major [bh][n][32], vv d-major [bh][32][n].
// grid (NT/64, 768/64, NB), block 256.
// ---------------------------------------------------------------------------
__global__ __launch_bounds__(256) void qkv_k(const __bf16* __restrict__ wqkv,
                                             const __bf16* __restrict__ xt,
                                             __bf16* __restrict__ qt,
                                             __bf16* __restrict__ kt,
                                             __bf16* __restrict__ vv) {
    __shared__ __align__(16) __bf16 BF[4][8][512];   // [js][kc][lane*8] 32 KB

    const int lane = threadIdx.x & 63, wv = threadIdx.x >> 6;
    const int g = lane >> 4, c16 = lane & 15;
    const int b    = blockIdx.z;
    const int o0   = blockIdx.y * 64 + wv * 16;
    const int tok0 = blockIdx.x * 64;

    // Stage B-tile: wave wv stages js=wv, kc=0..7 (1 KB chunks, lane-order).
    const __bf16* bsrc = xt + ((size_t)(b * NT + tok0 + wv * 16 + c16)) * CC + g * 8;
#pragma unroll
    for (int kc = 0; kc < 8; ++kc) {
        __builtin_amdgcn_global_load_lds(
            (const __attribute__((address_space(1))) void*)(bsrc + kc * 32),
            (__attribute__((address_space(3))) void*)&BF[wv][kc][0],
            16, 0, 0);
    }

    // Preload A rows (o0+c16, all 8 k-chunks) while the stage is in flight.
    const __bf16* arow = wqkv + (size_t)(o0 + c16) * CC + g * 8;
    bf16x8 a[8];
#pragma unroll
    for (int kc = 0; kc < 8; ++kc) a[kc] = *(const bf16x8_ma*)(arow + kc * 32);

    __syncthreads();   // drains vmcnt(0): stage + A-loads complete

    f32x4 acc[4];
#pragma unroll
    for (int i = 0; i < 4; ++i) acc[i] = zero4();

#pragma unroll
    for (int kc = 0; kc < 8; ++kc) {
#pragma unroll
        for (int js = 0; js < 4; ++js) {
            bf16x8 bb = *(const bf16x8_ma*)&BF[js][kc][lane * 8];
            acc[js] = __builtin_amdgcn_mfma_f32_16x16x32_bf16(a[kc], bb, acc[js], 0, 0, 0);
        }
    }

    const int reg = o0 >> 8;                 // 0=q, 1=k, 2=v (wave-uniform)
    const int oo0 = (o0 & 255) + g * 4;
    const int h   = oo0 >> 5;
    const int dd0 = oo0 & 31;
    const size_t bh = (size_t)(b * NHD + h);

#pragma unroll
    for (int js = 0; js < 4; ++js) {
        const int tok = tok0 + js * 16 + c16;
        if (reg == 0) {
            bf16x4 pk;
#pragma unroll
            for (int r = 0; r < 4; ++r) pk[r] = (__bf16)(acc[js][r] * QSCALE);
            *(bf16x4_ma*)(qt + (bh * NT + tok) * HD + dd0) = pk;
        } else if (reg == 1) {
            bf16x4 pk;
#pragma unroll
            for (int r = 0; r < 4; ++r) pk[r] = (__bf16)acc[js][r];
            *(bf16x4_ma*)(kt + (bh * NT + tok) * HD + dd0) = pk;
        } else {
#pragma unroll
            for (int r = 0; r < 4; ++r)
                vv[(bh * HD + dd0 + r) * NT + tok] = (__bf16)acc[js][r];
        }
    }
}

// ---------------------------------------------------------------------------
// Kernel 3: MFMA flash attention, 32x32 swapped-operand, in-register P,
// block-shared LDS K/V, 4-buffer counted-vmcnt pipeline (T3/T4) + setprio.
// Block 256 thr = 4 waves x 32 queries = 128 q/block; all waves sweep full j.
// Steady state: stages for tiles t+1,t+2 (4 loads/wave) stay in flight
// ACROSS the raw s_barrier; vmcnt(4) waits only for tile t's 2 loads.
// sched_barrier(0) before each TILE_WAIT pins MFMAs/ds_reads on the correct
// side of the barrier (hipcc may otherwise sink register-only MFMAs).
// Epilogue peels t=61/62/63 at vmcnt(4/2/0).
// grid (NT/128, NB*NHD) = 512 blocks, LDS 32KB, 2 blocks/CU.
// ---------------------------------------------------------------------------
__global__ __launch_bounds__(256, 2) void attn_k(const __bf16* __restrict__ qt,
                                                 const __bf16* __restrict__ kt,
                                                 const __bf16* __restrict__ vv,
                                                 __bf16* __restrict__ ao) {
    // Fragment lane-order tiles: [buf][js][half][lane*8 bf16]
    __shared__ __align__(16) __bf16 KF[4][2][2][512];   // 16 KB
    __shared__ __align__(16) __bf16 VF[4][2][2][512];   // 16 KB

    const int tid  = threadIdx.x;
    const int lane = tid & 63, wv = tid >> 6;          // wv 0..3
    const int c32 = lane & 31, hi = lane >> 5;
    const int bh = blockIdx.y;
    const int b = bh >> 3, h = bh & 7;
    const int i0q = blockIdx.x * 128 + wv * 32;        // this wave: 32 queries

    const __bf16* qbase = qt + ((size_t)bh * NT + i0q) * HD;
    const __bf16* kbase = kt + (size_t)bh * NT * HD;
    const __bf16* vbase = vv + (size_t)bh * HD * NT;

    // Staging role of this wave: K chunk (stg_js, kk=stg_sl), V chunk (stg_js, vslot=stg_sl)
    const int stg_js = wv & 1, stg_sl = wv >> 1;

    // Q fragments (B operand of score MFMA): row=q=c32, k = kk*16 + hi*8 + e
    bf16x8 aq0 = *(const bf16x8_ma*)(qbase + (size_t)c32 * HD + hi * 8);
    bf16x8 aq1 = *(const bf16x8_ma*)(qbase + (size_t)c32 * HD + 16 + hi * 8);

    f32x16 oacc = zero16();      // D[q_row][d_col]: rows=q, cols=d=c32
    float rsa[4] = {0.f, 0.f, 0.f, 0.f};   // 4 independent partial-l chains

#define STAGE(bf, jb) do {                                                              \
    const __bf16* gk = kbase + (size_t)((jb) + stg_js * 32 + c32) * HD                  \
                             + stg_sl * 16 + hi * 8;                                    \
    __builtin_amdgcn_global_load_lds(                                                   \
        (const __attribute__((address_space(1))) void*)gk,                              \
        (__attribute__((address_space(3))) void*)&KF[bf][stg_js][stg_sl][0],            \
        16, 0, 0);                                                                      \
    const __bf16* gv = vbase + (size_t)c32 * NT + (jb) + stg_js * 32                    \
                             + stg_sl * 16 + hi * 8;                                    \
    __builtin_amdgcn_global_load_lds(                                                   \
        (const __attribute__((address_space(1))) void*)gv,                              \
        (__attribute__((address_space(3))) void*)&VF[bf][stg_js][stg_sl][0],            \
        16, 0, 0);                                                                      \
} while (0)

#define SUBTILE(bf, js) do {                                                            \
    bf16x8 fk0 = *(const bf16x8_ma*)&KF[bf][js][0][lane * 8];                           \
    bf16x8 fk1 = *(const bf16x8_ma*)&KF[bf][js][1][lane * 8];                           \
    bf16x8 fv0 = *(const bf16x8_ma*)&VF[bf][js][0][lane * 8];                           \
    bf16x8 fv1 = *(const bf16x8_ma*)&VF[bf][js][1][lane * 8];                           \
    f32x16 s = __builtin_amdgcn_mfma_f32_32x32x16_bf16(fk0, aq0, zero16(), 0, 0, 0);    \
    s = __builtin_amdgcn_mfma_f32_32x32x16_bf16(fk1, aq1, s, 0, 0, 0);                  \
    float p[16];                                                                        \
    _Pragma("unroll")                                                                   \
    for (int r = 0; r < 16; ++r) {                                                      \
        p[r] = __builtin_amdgcn_exp2f(s[r]);                                            \
        rsa[r & 3] += p[r];                                                             \
    }                                                                                   \
    unsigned pk[8];                                                                     \
    _Pragma("unroll")                                                                   \
    for (int i = 0; i < 8; ++i) CVT_PK(pk[i], p[2 * i], p[2 * i + 1]);                  \
    PLSWAP(pk[0], pk[2]);                                                               \
    PLSWAP(pk[1], pk[3]);                                                               \
    PLSWAP(pk[4], pk[6]);                                                               \
    PLSWAP(pk[5], pk[7]);                                                               \
    u32x4 a0 = {pk[0], pk[1], pk[2], pk[3]};                                            \
    u32x4 a1 = {pk[4], pk[5], pk[6], pk[7]};                                            \
    const bf16x8 ap0 = __builtin_bit_cast(bf16x8, a0);                                  \
    const bf16x8 ap1 = __builtin_bit_cast(bf16x8, a1);                                  \
    oacc = __builtin_amdgcn_mfma_f32_32x32x16_bf16(ap0, fv0, oacc, 0, 0, 0);            \
    oacc = __builtin_amdgcn_mfma_f32_32x32x16_bf16(ap1, fv1, oacc, 0, 0, 0);            \
} while (0)

// One pipelined tile step: pin program order (no MFMA/ds_read may cross),
// wait own tile-t loads (vmcnt VM), cross-wave barrier, fence.
#define TILE_WAIT(VMC) do {                                                             \
    __builtin_amdgcn_sched_barrier(0);                                                  \
    asm volatile("s_waitcnt vmcnt(" #VMC ")" ::: "memory");                             \
    __builtin_amdgcn_s_barrier();                                                       \
    asm volatile("" ::: "memory");                                                      \
    __builtin_amdgcn_sched_barrier(0);                                                  \
} while (0)

    const int NTILES = NT / 64;   // 64

    // Prologue: stage tiles 0,1,2 into bufs 0,1,2 (6 loads in flight).
    STAGE(0, 0);
    STAGE(1, 64);
    STAGE(2, 128);
    __builtin_amdgcn_sched_barrier(0);

    int t = 0;
#pragma unroll 1
    for (; t < NTILES - 3; ++t) {
        TILE_WAIT(4);                       // tile t ready (4 newer loads in flight)
        STAGE((t + 3) & 3, (t + 3) * 64);   // overwrites buf of tile t-1 (all waves past it)
        __builtin_amdgcn_s_setprio(1);
        SUBTILE(t & 3, 0);
        SUBTILE(t & 3, 1);
        __builtin_amdgcn_s_setprio(0);
    }
    // t = 61: tiles 61,62,63 in flight (6 loads)
    TILE_WAIT(4);
    __builtin_amdgcn_s_setprio(1);
    SUBTILE(61 & 3, 0); SUBTILE(61 & 3, 1);
    __builtin_amdgcn_s_setprio(0);
    // t = 62: tiles 62,63 in flight (4 loads)
    TILE_WAIT(2);
    __builtin_amdgcn_s_setprio(1);
    SUBTILE(62 & 3, 0); SUBTILE(62 & 3, 1);
    __builtin_amdgcn_s_setprio(0);
    // t = 63: tile 63 in flight (2 loads)
    TILE_WAIT(0);
    __builtin_amdgcn_s_setprio(1);
    SUBTILE(63 & 3, 0); SUBTILE(63 & 3, 1);
    __builtin_amdgcn_s_setprio(0);

#undef STAGE
#undef SUBTILE
#undef TILE_WAIT

    float rs = (rsa[0] + rsa[1]) + (rsa[2] + rsa[3]);
    // complete per-query l: lane and lane^32 each summed half the j's of q=c32
    rs += __shfl_xor(rs, 32, 64);

    // Direct epilogue: oacc rows q = 8*g4 + 4*hi + r, cols d = c32.
#pragma unroll
    for (int g4 = 0; g4 < 4; ++g4) {
#pragma unroll
        for (int r = 0; r < 4; ++r) {
            const int q = 8 * g4 + 4 * hi + r;
            const float lt = __shfl(rs, q, 64);
            ao[((size_t)(b * NT) + i0q + q) * CC + h * HD + c32] =
                (__bf16)(oacc[4 * g4 + r] / lt);
        }
    }
}

// ---------------------------------------------------------------------------
// Kernel 4: proj GEMM + residual (MFMA), F32 output, B-tile LDS-shared.
// grid (NT/64, CC/64, NB), block 256.
// ---------------------------------------------------------------------------
__global__ __launch_bounds__(256) void proj_k(const __bf16* __restrict__ wp,
                                              const __bf16* __restrict__ ao,
                                              const float* __restrict__ x,
                                              float* __restrict__ out) {
    __shared__ __align__(16) __bf16 BF[4][8][512];   // [js][kc][lane*8] 32 KB

    const int lane = threadIdx.x & 63, wv = threadIdx.x >> 6;
    const int g = lane >> 4, c16 = lane & 15;
    const int b    = blockIdx.z;
    const int o0   = blockIdx.y * 64 + wv * 16;
    const int tok0 = blockIdx.x * 64;

    // Stage B-tile (ao rows) once per block, fragment lane-order.
    const __bf16* bsrc = ao + ((size_t)(b * NT + tok0 + wv * 16 + c16)) * CC + g * 8;
#pragma unroll
    for (int kc = 0; kc < 8; ++kc) {
        __builtin_amdgcn_global_load_lds(
            (const __attribute__((address_space(1))) void*)(bsrc + kc * 32),
            (__attribute__((address_space(3))) void*)&BF[wv][kc][0],
            16, 0, 0);
    }

    const __bf16* arow = wp + (size_t)(o0 + c16) * CC + g * 8;
    bf16x8 a[8];
#pragma unroll
    for (int kc = 0; kc < 8; ++kc) a[kc] = *(const bf16x8_ma*)(arow + kc * 32);

    __syncthreads();

    f32x4 acc[4];
#pragma unroll
    for (int i = 0; i < 4; ++i) acc[i] = zero4();

#pragma unroll
    for (int kc = 0; kc < 8; ++kc) {
#pragma unroll
        for (int js = 0; js < 4; ++js) {
            bf16x8 bb = *(const bf16x8_ma*)&BF[js][kc][lane * 8];
            acc[js] = __builtin_amdgcn_mfma_f32_16x16x32_bf16(a[kc], bb, acc[js], 0, 0, 0);
        }
    }

#pragma unroll
    for (int js = 0; js < 4; ++js) {
        const int tok = tok0 + js * 16 + c16;
#pragma unroll
        for (int r = 0; r < 4; ++r) {
            const int o = o0 + g * 4 + r;
            const size_t idx = ((size_t)(b * CC + o)) * NT + tok;
            out[idx] = acc[js][r] + x[idx];
        }
    }
}

// ---------------------------------------------------------------------------
extern "C" void kernel_launch(void* const* d_in, const int* in_sizes, int n_in,
                              void* d_out, int out_size, void* d_ws, size_t ws_size,
                              hipStream_t stream) {
    const int SX  = NB * CC * NT;   // 2,097,152
    const int SW3 = 3 * CC * CC;    //   196,608
    const int SW1 = CC * CC;        //    65,536
    const size_t E = (size_t)SX;

    const float* x  = nullptr;
    const float* wq = nullptr;
    const float* wp = nullptr;
    for (int i = 0; i < n_in; ++i) {
        const int sz = in_sizes[i];
        if (sz == SX || sz == 2 * SX || sz == 4 * SX)           x  = (const float*)d_in[i];
        else if (sz == SW3 || sz == 2 * SW3 || sz == 4 * SW3)   wq = (const float*)d_in[i];
        else if (sz == SW1 || sz == 2 * SW1 || sz == 4 * SW1)   wp = (const float*)d_in[i];
    }
    if (!x || !wq || !wp) {
        x  = (const float*)d_in[0];
        wq = (const float*)d_in[1];
        wp = (const float*)d_in[2];
    }

    // Workspace (bf16 elements), 16.5 MB total (proven):
    __bf16* ws  = (__bf16*)d_ws;
    __bf16* wqb = ws;
    __bf16* wpb = wqb + SW3;
    __bf16* xt  = wpb + SW1;             // becomes ao after qkv_k
    __bf16* qt  = xt + E;
    __bf16* kt  = qt + E;
    __bf16* vv  = kt + E;
    __bf16* ao  = xt;

    float* out = (float*)d_out;

    convw_k<<<dim3((SW3 + SW1 + 255) / 256), 256, 0, stream>>>(wq, wqb, SW3, wp, wpb, SW1);
    transpose_k<<<dim3(NT / 64, CC / 64, NB), 256, 0, stream>>>(x, xt);
    qkv_k<<<dim3(NT / 64, (3 * CC) / 64, NB), 256, 0, stream>>>(wqb, xt, qt, kt, vv);
    attn_k<<<dim3(NT / 128, NB * NHD), 256, 0, stream>>>(qt, kt, vv, ao);
    proj_k<<<dim3(NT / 64, CC / 64, NB), 256, 0, stream>>>(wpb, ao, x, out);
}

// Round 8
// 142.858 us; speedup vs baseline: 1.8084x; 1.0618x over previous
//
#include <hip/hip_runtime.h>
#include <hip/hip_bf16.h>

// Problem constants
#define NB  2      // batch
#define CC  256    // channels
#define NHD 8      // heads
#define HD  32     // head dim
#define NT  4096   // tokens = H*W

typedef __bf16 bf16x8 __attribute__((ext_vector_type(8)));
typedef bf16x8 bf16x8_ma __attribute__((may_alias));
typedef __bf16 bf16x4 __attribute__((ext_vector_type(4)));
typedef bf16x4 bf16x4_ma __attribute__((may_alias));
typedef float  f32x4  __attribute__((ext_vector_type(4)));
typedef f32x4  f32x4_ma __attribute__((may_alias));
typedef float  f32x16 __attribute__((ext_vector_type(16)));
typedef unsigned int u32x4 __attribute__((ext_vector_type(4)));

static __device__ __forceinline__ f32x4 zero4() {
    f32x4 z = {0.f, 0.f, 0.f, 0.f}; return z;
}
static __device__ __forceinline__ f32x16 zero16() {
    f32x16 z = {0.f,0.f,0.f,0.f,0.f,0.f,0.f,0.f,
                0.f,0.f,0.f,0.f,0.f,0.f,0.f,0.f};
    return z;
}

// q pre-scale: log2(e) / sqrt(32)
#define QSCALE 0.25505392421795654f

// v_cvt_pk_bf16_f32: dst.lo = bf16(lo), dst.hi = bf16(hi)  (no builtin on gfx950)
#define CVT_PK(dst, lo, hi_) \
    asm("v_cvt_pk_bf16_f32 %0, %1, %2" : "=v"(dst) : "v"(lo), "v"(hi_))
// v_permlane32_swap_b32: x[32:63] <-> y[0:31]
#define PLSWAP(x, y) \
    asm("v_permlane32_swap_b32 %0, %1" : "+v"(x), "+v"(y))

// ---------------------------------------------------------------------------
// ROUND 25: R24 post-mortem -- qkv/proj LDS-share won (~18us); attn counted-
// vmcnt pipeline REGRESSED (66.5 -> 69.9): revert attn loop to proven R22
// form. attn's limiter: fixed VALU work (28.7us issue = 41% busy) with only
// 2 waves/SIMD (grid-capped 2 blocks/CU) to fill gaps. Fix: j-split across
// blocks (gridDim.z = 2) -- occupancy 2x with ZERO extra K/V line requests
// (each block reads only its j-half; shrinking q-tiles instead would double
// traffic, the R21 lesson). Blocks write f32 partial (O,l); comb_k combines.
// Workspace-guarded: falls back to JSEG=1 (exact R22 path) if ws too small.
// ---------------------------------------------------------------------------

// ---------------------------------------------------------------------------
// Kernel 0: f32 -> bf16 convert, both weight arrays in one launch.
// ---------------------------------------------------------------------------
__global__ __launch_bounds__(256) void convw_k(const float* __restrict__ s1,
                                               __bf16* __restrict__ d1, int n1,
                                               const float* __restrict__ s2,
                                               __bf16* __restrict__ d2, int n2) {
    const int i = blockIdx.x * 256 + threadIdx.x;
    if (i < n1) d1[i] = (__bf16)s1[i];
    else if (i - n1 < n2) d2[i - n1] = (__bf16)s2[i - n1];
}

// ---------------------------------------------------------------------------
// Kernel 1: LDS-tiled transpose+convert x f32 [b][c][n] -> xt bf16 [b][n][c].
// ---------------------------------------------------------------------------
__global__ __launch_bounds__(256) void transpose_k(const float* __restrict__ x,
                                                   __bf16* __restrict__ xt) {
    __shared__ __bf16 T[64][65];
    const int tid = threadIdx.x;
    const int n0 = blockIdx.x * 64, c0 = blockIdx.y * 64, b = blockIdx.z;

#pragma unroll
    for (int rep = 0; rep < 16; ++rep) {
        const int e = rep * 256 + tid;
        const int cl = e >> 6, nl = e & 63;
        T[nl][cl] = (__bf16)x[((size_t)(b * CC + c0 + cl)) * NT + n0 + nl];
    }
    __syncthreads();
#pragma unroll
    for (int rep = 0; rep < 16; ++rep) {
        const int e = rep * 256 + tid;
        const int nl = e >> 6, cl = e & 63;
        xt[((size_t)(b * NT + n0 + nl)) * CC + c0 + cl] = T[nl][cl];
    }
}

// ---------------------------------------------------------------------------
// Kernel 2: QKV GEMM (MFMA), B-tile LDS-shared (proven R24).
// grid (NT/64, 768/64, NB), block 256.
// ---------------------------------------------------------------------------
__global__ __launch_bounds__(256) void qkv_k(const __bf16* __restrict__ wqkv,
                                             const __bf16* __restrict__ xt,
                                             __bf16* __restrict__ qt,
                                             __bf16* __restrict__ kt,
                                             __bf16* __restrict__ vv) {
    __shared__ __align__(16) __bf16 BF[4][8][512];   // [js][kc][lane*8] 32 KB

    const int lane = threadIdx.x & 63, wv = threadIdx.x >> 6;
    const int g = lane >> 4, c16 = lane & 15;
    const int b    = blockIdx.z;
    const int o0   = blockIdx.y * 64 + wv * 16;
    const int tok0 = blockIdx.x * 64;

    // Stage B-tile: wave wv stages js=wv, kc=0..7 (1 KB chunks, lane-order).
    const __bf16* bsrc = xt + ((size_t)(b * NT + tok0 + wv * 16 + c16)) * CC + g * 8;
#pragma unroll
    for (int kc = 0; kc < 8; ++kc) {
        __builtin_amdgcn_global_load_lds(
            (const __attribute__((address_space(1))) void*)(bsrc + kc * 32),
            (__attribute__((address_space(3))) void*)&BF[wv][kc][0],
            16, 0, 0);
    }

    // Preload A rows (o0+c16, all 8 k-chunks) while the stage is in flight.
    const __bf16* arow = wqkv + (size_t)(o0 + c16) * CC + g * 8;
    bf16x8 a[8];
#pragma unroll
    for (int kc = 0; kc < 8; ++kc) a[kc] = *(const bf16x8_ma*)(arow + kc * 32);

    __syncthreads();   // drains vmcnt(0): stage + A-loads complete

    f32x4 acc[4];
#pragma unroll
    for (int i = 0; i < 4; ++i) acc[i] = zero4();

#pragma unroll
    for (int kc = 0; kc < 8; ++kc) {
#pragma unroll
        for (int js = 0; js < 4; ++js) {
            bf16x8 bb = *(const bf16x8_ma*)&BF[js][kc][lane * 8];
            acc[js] = __builtin_amdgcn_mfma_f32_16x16x32_bf16(a[kc], bb, acc[js], 0, 0, 0);
        }
    }

    const int reg = o0 >> 8;                 // 0=q, 1=k, 2=v (wave-uniform)
    const int oo0 = (o0 & 255) + g * 4;
    const int h   = oo0 >> 5;
    const int dd0 = oo0 & 31;
    const size_t bh = (size_t)(b * NHD + h);

#pragma unroll
    for (int js = 0; js < 4; ++js) {
        const int tok = tok0 + js * 16 + c16;
        if (reg == 0) {
            bf16x4 pk;
#pragma unroll
            for (int r = 0; r < 4; ++r) pk[r] = (__bf16)(acc[js][r] * QSCALE);
            *(bf16x4_ma*)(qt + (bh * NT + tok) * HD + dd0) = pk;
        } else if (reg == 1) {
            bf16x4 pk;
#pragma unroll
            for (int r = 0; r < 4; ++r) pk[r] = (__bf16)acc[js][r];
            *(bf16x4_ma*)(kt + (bh * NT + tok) * HD + dd0) = pk;
        } else {
#pragma unroll
            for (int r = 0; r < 4; ++r)
                vv[(bh * HD + dd0 + r) * NT + tok] = (__bf16)acc[js][r];
        }
    }
}

// ---------------------------------------------------------------------------
// Kernel 3: MFMA flash attention, 32x32 swapped-operand, in-register P,
// block-shared LDS K/V (R22 proven loop: 2 buffers, vmcnt(0)+syncthreads).
// Block 256 thr = 4 waves x 32 queries = 128 q/block; block sweeps the
// j-range of its gridDim.z segment (seg = blockIdx.z).
// JSEG=2: writes f32 partial (O,l) to PO/PL; JSEG=1: writes ao directly.
// grid (NT/128, NB*NHD, JSEG), LDS 16KB.
// ---------------------------------------------------------------------------
__global__ __launch_bounds__(256, 4) void attn_k(const __bf16* __restrict__ qt,
                                                 const __bf16* __restrict__ kt,
                                                 const __bf16* __restrict__ vv,
                                                 __bf16* __restrict__ ao,
                                                 float* __restrict__ PO,
                                                 float* __restrict__ PL) {
    // Fragment lane-order tiles: [buf][js][half][lane*8 bf16]
    __shared__ __align__(16) __bf16 KF[2][2][2][512];   // 8 KB
    __shared__ __align__(16) __bf16 VF[2][2][2][512];   // 8 KB

    const int tid  = threadIdx.x;
    const int lane = tid & 63, wv = tid >> 6;          // wv 0..3
    const int c32 = lane & 31, hi = lane >> 5;
    const int bh = blockIdx.y;
    const int b = bh >> 3, h = bh & 7;
    const int seg = blockIdx.z, nseg = gridDim.z;
    const int i0q = blockIdx.x * 128 + wv * 32;        // this wave: 32 queries

    const __bf16* qbase = qt + ((size_t)bh * NT + i0q) * HD;
    const __bf16* kbase = kt + (size_t)bh * NT * HD;
    const __bf16* vbase = vv + (size_t)bh * HD * NT;

    // Staging role of this wave: K chunk (stg_js, kk=stg_sl), V chunk (stg_js, vslot=stg_sl)
    const int stg_js = wv & 1, stg_sl = wv >> 1;

    // Q fragments (B operand of score MFMA): row=q=c32, k = kk*16 + hi*8 + e
    bf16x8 aq0 = *(const bf16x8_ma*)(qbase + (size_t)c32 * HD + hi * 8);
    bf16x8 aq1 = *(const bf16x8_ma*)(qbase + (size_t)c32 * HD + 16 + hi * 8);

    f32x16 oacc = zero16();      // D[q_row][d_col]: rows=q, cols=d=c32
    float rsa[4] = {0.f, 0.f, 0.f, 0.f};   // 4 independent partial-l chains

#define STAGE(bf, jb) do {                                                              \
    const __bf16* gk = kbase + (size_t)((jb) + stg_js * 32 + c32) * HD                  \
                             + stg_sl * 16 + hi * 8;                                    \
    __builtin_amdgcn_global_load_lds(                                                   \
        (const __attribute__((address_space(1))) void*)gk,                              \
        (__attribute__((address_space(3))) void*)&KF[bf][stg_js][stg_sl][0],            \
        16, 0, 0);                                                                      \
    const __bf16* gv = vbase + (size_t)c32 * NT + (jb) + stg_js * 32                    \
                             + stg_sl * 16 + hi * 8;                                    \
    __builtin_amdgcn_global_load_lds(                                                   \
        (const __attribute__((address_space(1))) void*)gv,                              \
        (__attribute__((address_space(3))) void*)&VF[bf][stg_js][stg_sl][0],            \
        16, 0, 0);                                                                      \
} while (0)

#define SUBTILE(bf, js) do {                                                            \
    bf16x8 fk0 = *(const bf16x8_ma*)&KF[bf][js][0][lane * 8];                           \
    bf16x8 fk1 = *(const bf16x8_ma*)&KF[bf][js][1][lane * 8];                           \
    bf16x8 fv0 = *(const bf16x8_ma*)&VF[bf][js][0][lane * 8];                           \
    bf16x8 fv1 = *(const bf16x8_ma*)&VF[bf][js][1][lane * 8];                           \
    f32x16 s = __builtin_amdgcn_mfma_f32_32x32x16_bf16(fk0, aq0, zero16(), 0, 0, 0);    \
    s = __builtin_amdgcn_mfma_f32_32x32x16_bf16(fk1, aq1, s, 0, 0, 0);                  \
    float p[16];                                                                        \
    _Pragma("unroll")                                                                   \
    for (int r = 0; r < 16; ++r) {                                                      \
        p[r] = __builtin_amdgcn_exp2f(s[r]);                                            \
        rsa[r & 3] += p[r];                                                             \
    }                                                                                   \
    unsigned pk[8];                                                                     \
    _Pragma("unroll")                                                                   \
    for (int i = 0; i < 8; ++i) CVT_PK(pk[i], p[2 * i], p[2 * i + 1]);                  \
    PLSWAP(pk[0], pk[2]);                                                               \
    PLSWAP(pk[1], pk[3]);                                                               \
    PLSWAP(pk[4], pk[6]);                                                               \
    PLSWAP(pk[5], pk[7]);                                                               \
    u32x4 a0 = {pk[0], pk[1], pk[2], pk[3]};                                            \
    u32x4 a1 = {pk[4], pk[5], pk[6], pk[7]};                                            \
    const bf16x8 ap0 = __builtin_bit_cast(bf16x8, a0);                                  \
    const bf16x8 ap1 = __builtin_bit_cast(bf16x8, a1);                                  \
    oacc = __builtin_amdgcn_mfma_f32_32x32x16_bf16(ap0, fv0, oacc, 0, 0, 0);            \
    oacc = __builtin_amdgcn_mfma_f32_32x32x16_bf16(ap1, fv1, oacc, 0, 0, 0);            \
} while (0)

    const int ntiles  = (NT / 64) / nseg;          // 64 (jseg=1) or 32 (jseg=2)
    const int j_begin = seg * ntiles * 64;

    // Prologue: stage tile 0 into buf 0.
    STAGE(0, j_begin);
    asm volatile("s_waitcnt vmcnt(0)" ::: "memory");
    __syncthreads();

    int buf = 0;
#pragma unroll 1
    for (int t = 0; t < ntiles; ++t) {
        if (t + 1 < ntiles) STAGE(buf ^ 1, j_begin + (t + 1) * 64);
        SUBTILE(buf, 0);
        SUBTILE(buf, 1);
        asm volatile("s_waitcnt vmcnt(0)" ::: "memory");
        __syncthreads();
        buf ^= 1;
    }

#undef STAGE
#undef SUBTILE

    float rs = (rsa[0] + rsa[1]) + (rsa[2] + rsa[3]);
    // complete per-query l: lane and lane^32 each summed half the j's of q=c32
    rs += __shfl_xor(rs, 32, 64);

    if (nseg == 1) {
        // Direct epilogue: oacc rows q = 8*g4 + 4*hi + r, cols d = c32.
#pragma unroll
        for (int g4 = 0; g4 < 4; ++g4) {
#pragma unroll
            for (int r = 0; r < 4; ++r) {
                const int q = 8 * g4 + 4 * hi + r;
                const float lt = __shfl(rs, q, 64);
                ao[((size_t)(b * NT) + i0q + q) * CC + h * HD + c32] =
                    (__bf16)(oacc[4 * g4 + r] / lt);
            }
        }
    } else {
        // Partial epilogue: PO [seg][bh][n][32] f32, PL [seg][bh][n] f32.
        float* po = PO + (((size_t)seg * NB * NHD + bh) * NT + i0q) * HD;
#pragma unroll
        for (int g4 = 0; g4 < 4; ++g4) {
#pragma unroll
            for (int r = 0; r < 4; ++r) {
                const int q = 8 * g4 + 4 * hi + r;
                po[(size_t)q * HD + c32] = oacc[4 * g4 + r];
            }
        }
        if (hi == 0)
            PL[((size_t)seg * NB * NHD + bh) * NT + i0q + c32] = rs;
    }
}

// ---------------------------------------------------------------------------
// Kernel 3b: combine JSEG=2 partials: ao = (O0+O1)/(l0+l1), bf16.
// One thread = 4 consecutive d of one (bh, n). grid 2048 x 256.
// ---------------------------------------------------------------------------
__global__ __launch_bounds__(256) void comb_k(const float* __restrict__ PO,
                                              const float* __restrict__ PL,
                                              __bf16* __restrict__ ao) {
    const int i = blockIdx.x * 256 + threadIdx.x;    // 0 .. 16*4096*8-1
    const int bh = i >> 15;                          // 8 groups * 4096 n
    const int rem = i & 32767;
    const int n = rem >> 3, g = rem & 7;
    const int b = bh >> 3, h = bh & 7;

    const size_t o0i = (((size_t)bh) * NT + n) * HD + g * 4;
    const size_t o1i = o0i + (size_t)(NB * NHD) * NT * HD;
    f32x4 o0 = *(const f32x4_ma*)&PO[o0i];
    f32x4 o1 = *(const f32x4_ma*)&PO[o1i];
    const float l = PL[(size_t)bh * NT + n] + PL[(size_t)(NB * NHD) * NT + (size_t)bh * NT + n];

    bf16x4 pk;
#pragma unroll
    for (int r = 0; r < 4; ++r) pk[r] = (__bf16)((o0[r] + o1[r]) / l);
    *(bf16x4_ma*)&ao[((size_t)(b * NT) + n) * CC + h * HD + g * 4] = pk;
}

// ---------------------------------------------------------------------------
// Kernel 4: proj GEMM + residual (MFMA), F32 output, B-tile LDS-shared.
// grid (NT/64, CC/64, NB), block 256.
// ---------------------------------------------------------------------------
__global__ __launch_bounds__(256) void proj_k(const __bf16* __restrict__ wp,
                                              const __bf16* __restrict__ ao,
                                              const float* __restrict__ x,
                                              float* __restrict__ out) {
    __shared__ __align__(16) __bf16 BF[4][8][512];   // [js][kc][lane*8] 32 KB

    const int lane = threadIdx.x & 63, wv = threadIdx.x >> 6;
    const int g = lane >> 4, c16 = lane & 15;
    const int b    = blockIdx.z;
    const int o0   = blockIdx.y * 64 + wv * 16;
    const int tok0 = blockIdx.x * 64;

    // Stage B-tile (ao rows) once per block, fragment lane-order.
    const __bf16* bsrc = ao + ((size_t)(b * NT + tok0 + wv * 16 + c16)) * CC + g * 8;
#pragma unroll
    for (int kc = 0; kc < 8; ++kc) {
        __builtin_amdgcn_global_load_lds(
            (const __attribute__((address_space(1))) void*)(bsrc + kc * 32),
            (__attribute__((address_space(3))) void*)&BF[wv][kc][0],
            16, 0, 0);
    }

    const __bf16* arow = wp + (size_t)(o0 + c16) * CC + g * 8;
    bf16x8 a[8];
#pragma unroll
    for (int kc = 0; kc < 8; ++kc) a[kc] = *(const bf16x8_ma*)(arow + kc * 32);

    __syncthreads();

    f32x4 acc[4];
#pragma unroll
    for (int i = 0; i < 4; ++i) acc[i] = zero4();

#pragma unroll
    for (int kc = 0; kc < 8; ++kc) {
#pragma unroll
        for (int js = 0; js < 4; ++js) {
            bf16x8 bb = *(const bf16x8_ma*)&BF[js][kc][lane * 8];
            acc[js] = __builtin_amdgcn_mfma_f32_16x16x32_bf16(a[kc], bb, acc[js], 0, 0, 0);
        }
    }

#pragma unroll
    for (int js = 0; js < 4; ++js) {
        const int tok = tok0 + js * 16 + c16;
#pragma unroll
        for (int r = 0; r < 4; ++r) {
            const int o = o0 + g * 4 + r;
            const size_t idx = ((size_t)(b * CC + o)) * NT + tok;
            out[idx] = acc[js][r] + x[idx];
        }
    }
}

// ---------------------------------------------------------------------------
extern "C" void kernel_launch(void* const* d_in, const int* in_sizes, int n_in,
                              void* d_out, int out_size, void* d_ws, size_t ws_size,
                              hipStream_t stream) {
    const int SX  = NB * CC * NT;   // 2,097,152
    const int SW3 = 3 * CC * CC;    //   196,608
    const int SW1 = CC * CC;        //    65,536
    const size_t E = (size_t)SX;

    const float* x  = nullptr;
    const float* wq = nullptr;
    const float* wp = nullptr;
    for (int i = 0; i < n_in; ++i) {
        const int sz = in_sizes[i];
        if (sz == SX || sz == 2 * SX || sz == 4 * SX)           x  = (const float*)d_in[i];
        else if (sz == SW3 || sz == 2 * SW3 || sz == 4 * SW3)   wq = (const float*)d_in[i];
        else if (sz == SW1 || sz == 2 * SW1 || sz == 4 * SW1)   wp = (const float*)d_in[i];
    }
    if (!x || !wq || !wp) {
        x  = (const float*)d_in[0];
        wq = (const float*)d_in[1];
        wp = (const float*)d_in[2];
    }

    // Workspace (bf16 elements), base 17.3 MB (proven):
    __bf16* ws  = (__bf16*)d_ws;
    __bf16* wqb = ws;
    __bf16* wpb = wqb + SW3;
    __bf16* xt  = wpb + SW1;             // becomes ao after qkv_k
    __bf16* qt  = xt + E;
    __bf16* kt  = qt + E;
    __bf16* vv  = kt + E;
    __bf16* ao  = xt;

    // Optional JSEG=2 partial buffers (f32), appended after vv:
    const size_t baseB = (size_t)(SW3 + SW1) * 2 + 4 * E * 2;       // bytes used
    const size_t poB   = 2ull * NB * NHD * NT * HD * 4;             // 16.78 MB
    const size_t plB   = 2ull * NB * NHD * NT * 4;                  //  0.52 MB
    const int jseg = (ws_size >= baseB + poB + plB) ? 2 : 1;
    float* PO = (float*)((char*)d_ws + baseB);
    float* PL = (float*)((char*)d_ws + baseB + poB);

    float* out = (float*)d_out;

    convw_k<<<dim3((SW3 + SW1 + 255) / 256), 256, 0, stream>>>(wq, wqb, SW3, wp, wpb, SW1);
    transpose_k<<<dim3(NT / 64, CC / 64, NB), 256, 0, stream>>>(x, xt);
    qkv_k<<<dim3(NT / 64, (3 * CC) / 64, NB), 256, 0, stream>>>(wqb, xt, qt, kt, vv);
    attn_k<<<dim3(NT / 128, NB * NHD, jseg), 256, 0, stream>>>(qt, kt, vv, ao, PO, PL);
    if (jseg == 2)
        comb_k<<<dim3((NB * NHD * NT * (HD / 4)) / 256), 256, 0, stream>>>(PO, PL, ao);
    proj_k<<<dim3(NT / 64, CC / 64, NB), 256, 0, stream>>>(wpb, ao, x, out);
}